// Round 1
// baseline (508.449 us; speedup 1.0000x reference)
//
#include <hip/hip_runtime.h>
#include <hip/hip_bf16.h>

// GCN 2-layer: h = relu(Agg(x@W1)+b1); out = Agg(h@W2)+b2
// Agg uses symmetric norm with self-loops, built as CSR-by-dst on device.

#define N_K 128  // inner dim for both GEMMs

// ---------------- degree / CSR build ----------------

__global__ void hist_kernel(const int* __restrict__ dst, int* __restrict__ cnt, int E) {
    int e = blockIdx.x * 256 + threadIdx.x;
    if (e < E) atomicAdd(&cnt[dst[e]], 1);
}

__global__ void finalize_deg(int* __restrict__ cnt, float* __restrict__ dinv, int n) {
    int i = blockIdx.x * 256 + threadIdx.x;
    if (i >= n) return;
    int d = cnt[i] + 1;              // + self loop
    cnt[i] = d;
    dinv[i] = rsqrtf((float)d);      // d >= 1 always
}

// block of 256 threads scans 1024 elements; writes inclusive scan to rp[1+i], block sum to bsum
__global__ void scan_block(const int* __restrict__ cnt, int* __restrict__ rp,
                           int* __restrict__ bsum, int n) {
    __shared__ int s[256];
    int t = threadIdx.x;
    int base = blockIdx.x * 1024 + t * 4;
    int v0 = (base + 0 < n) ? cnt[base + 0] : 0;
    int v1 = (base + 1 < n) ? cnt[base + 1] : 0;
    int v2 = (base + 2 < n) ? cnt[base + 2] : 0;
    int v3 = (base + 3 < n) ? cnt[base + 3] : 0;
    v1 += v0; v2 += v1; v3 += v2;    // inclusive within thread
    s[t] = v3;
    __syncthreads();
    for (int off = 1; off < 256; off <<= 1) {
        int tv = (t >= off) ? s[t - off] : 0;
        __syncthreads();
        s[t] += tv;
        __syncthreads();
    }
    int prefix = (t > 0) ? s[t - 1] : 0;
    if (base + 0 < n) rp[1 + base + 0] = prefix + v0;
    if (base + 1 < n) rp[1 + base + 1] = prefix + v1;
    if (base + 2 < n) rp[1 + base + 2] = prefix + v2;
    if (base + 3 < n) rp[1 + base + 3] = prefix + v3;
    if (t == 255) bsum[blockIdx.x] = s[255];
}

// single block of 128 threads: exclusive-scan bsum[0..nb), nb <= 128
__global__ void scan_bsum(int* __restrict__ bsum, int nb) {
    __shared__ int s[128];
    int t = threadIdx.x;
    int v = (t < nb) ? bsum[t] : 0;
    s[t] = v;
    __syncthreads();
    for (int off = 1; off < 128; off <<= 1) {
        int tv = (t >= off) ? s[t - off] : 0;
        __syncthreads();
        s[t] += tv;
        __syncthreads();
    }
    if (t < nb) bsum[t] = (t > 0) ? s[t - 1] : 0;
}

__global__ void scan_add(int* __restrict__ rp, const int* __restrict__ bsum, int n) {
    int i = blockIdx.x * 256 + threadIdx.x;
    if (i == 0) rp[0] = 0;
    if (i < n) rp[1 + i] += bsum[i >> 10];
}

__global__ void cursor_init(int* __restrict__ cursor, const int* __restrict__ rp, int n) {
    int i = blockIdx.x * 256 + threadIdx.x;
    if (i < n) cursor[i] = rp[i];
}

__global__ void fill_edges(const int* __restrict__ src, const int* __restrict__ dst,
                           const float* __restrict__ dinv, int* __restrict__ cursor,
                           int* __restrict__ edata, int E) {
    int e = blockIdx.x * 256 + threadIdx.x;
    if (e >= E) return;
    int s = src[e], d = dst[e];
    int pos = atomicAdd(&cursor[d], 1);
    edata[2 * pos]     = s;
    edata[2 * pos + 1] = __float_as_int(dinv[s] * dinv[d]);
}

__global__ void fill_self(const float* __restrict__ dinv, int* __restrict__ cursor,
                          int* __restrict__ edata, int n) {
    int i = blockIdx.x * 256 + threadIdx.x;
    if (i >= n) return;
    int pos = atomicAdd(&cursor[i], 1);
    float w = dinv[i];
    edata[2 * pos]     = i;
    edata[2 * pos + 1] = __float_as_int(w * w);
}

// ---------------- GEMM: H[n x COLS] = X[n x 128] @ W[128 x COLS] ----------------
// block 256 threads, 32 rows per block, k-tiled by 32.

template <int COLS>
__launch_bounds__(256)
__global__ void gemm_k128(const float* __restrict__ X, const float* __restrict__ W,
                          float* __restrict__ H, int n) {
    constexpr int NCG = COLS / 8;       // col groups: 16 (COLS=128) or 8 (COLS=64)
    constexpr int NRG = 256 / NCG;      // row groups: 16 or 32
    constexpr int RPT = 32 / NRG;       // rows per thread: 2 or 1
    __shared__ float sX[32][36];        // stride 36 floats: 16B-aligned rows, conflict-spread
    __shared__ float sW[32 * COLS];

    const int t  = threadIdx.x;
    const int cg = t % NCG;
    const int rg = t / NCG;
    const int row0 = blockIdx.x * 32;

    float acc[RPT][8];
#pragma unroll
    for (int i = 0; i < RPT; ++i)
#pragma unroll
        for (int j = 0; j < 8; ++j) acc[i][j] = 0.f;

    for (int k0 = 0; k0 < N_K; k0 += 32) {
        {   // load X tile: 32 rows x 32 k, one float4 per thread
            int r = t >> 3, kq = t & 7;
            int grow = row0 + r;
            float4 v = make_float4(0.f, 0.f, 0.f, 0.f);
            if (grow < n) v = *(const float4*)&X[grow * N_K + k0 + kq * 4];
            *(float4*)&sX[r][kq * 4] = v;
        }
        {   // load W tile: contiguous 32*COLS floats
            const float4* Wg = (const float4*)(W + k0 * COLS);
            float4* sW4 = (float4*)sW;
            constexpr int NV = (32 * COLS) / 4 / 256;   // 4 or 2
#pragma unroll
            for (int i = 0; i < NV; ++i) sW4[t + i * 256] = Wg[t + i * 256];
        }
        __syncthreads();
#pragma unroll
        for (int kk = 0; kk < 32; ++kk) {
            float4 w0 = *(const float4*)&sW[kk * COLS + cg * 8];
            float4 w1 = *(const float4*)&sW[kk * COLS + cg * 8 + 4];
#pragma unroll
            for (int i = 0; i < RPT; ++i) {
                float xv = sX[rg + i * NRG][kk];
                acc[i][0] += xv * w0.x; acc[i][1] += xv * w0.y;
                acc[i][2] += xv * w0.z; acc[i][3] += xv * w0.w;
                acc[i][4] += xv * w1.x; acc[i][5] += xv * w1.y;
                acc[i][6] += xv * w1.z; acc[i][7] += xv * w1.w;
            }
        }
        __syncthreads();
    }
#pragma unroll
    for (int i = 0; i < RPT; ++i) {
        int grow = row0 + rg + i * NRG;
        if (grow < n) {
            *(float4*)&H[grow * COLS + cg * 8]     = make_float4(acc[i][0], acc[i][1], acc[i][2], acc[i][3]);
            *(float4*)&H[grow * COLS + cg * 8 + 4] = make_float4(acc[i][4], acc[i][5], acc[i][6], acc[i][7]);
        }
    }
}

// ---------------- aggregation: out[n] = sum_{e in CSR(n)} norm_e * H[src_e] + b ----------------
// one 64-lane wave per node.

template <int D, bool RELU>
__launch_bounds__(256)
__global__ void aggregate(const float* __restrict__ H, const int* __restrict__ rp,
                          const int* __restrict__ edata, const float* __restrict__ bias,
                          float* __restrict__ out, int n) {
    int gw   = (blockIdx.x * 256 + threadIdx.x) >> 6;
    int lane = threadIdx.x & 63;
    if (gw >= n) return;
    int e = rp[gw], end = rp[gw + 1];

    if constexpr (D == 128) {
        float ax = 0.f, ay = 0.f;
        for (; e + 2 <= end; e += 2) {
            int2 m0 = *(const int2*)&edata[2 * e];
            int2 m1 = *(const int2*)&edata[2 * e + 2];
            float2 v0 = *(const float2*)&H[m0.x * 128 + lane * 2];
            float2 v1 = *(const float2*)&H[m1.x * 128 + lane * 2];
            float w0 = __int_as_float(m0.y), w1 = __int_as_float(m1.y);
            ax += w0 * v0.x; ay += w0 * v0.y;
            ax += w1 * v1.x; ay += w1 * v1.y;
        }
        if (e < end) {
            int2 m = *(const int2*)&edata[2 * e];
            float2 v = *(const float2*)&H[m.x * 128 + lane * 2];
            float w = __int_as_float(m.y);
            ax += w * v.x; ay += w * v.y;
        }
        ax += bias[lane * 2]; ay += bias[lane * 2 + 1];
        if (RELU) { ax = fmaxf(ax, 0.f); ay = fmaxf(ay, 0.f); }
        *(float2*)&out[gw * 128 + lane * 2] = make_float2(ax, ay);
    } else {
        float a = 0.f;
        for (; e + 2 <= end; e += 2) {
            int2 m0 = *(const int2*)&edata[2 * e];
            int2 m1 = *(const int2*)&edata[2 * e + 2];
            float v0 = H[m0.x * 64 + lane];
            float v1 = H[m1.x * 64 + lane];
            a += __int_as_float(m0.y) * v0;
            a += __int_as_float(m1.y) * v1;
        }
        if (e < end) {
            int2 m = *(const int2*)&edata[2 * e];
            a += __int_as_float(m.y) * H[m.x * 64 + lane];
        }
        a += bias[lane];
        if (RELU) a = fmaxf(a, 0.f);
        out[gw * 64 + lane] = a;
    }
}

__global__ void zero_out(float* __restrict__ out, int n) {
    int i = blockIdx.x * 256 + threadIdx.x;
    if (i < n) out[i] = 0.f;
}

// ---------------- launch ----------------

extern "C" void kernel_launch(void* const* d_in, const int* in_sizes, int n_in,
                              void* d_out, int out_size, void* d_ws, size_t ws_size,
                              hipStream_t stream) {
    const float* x  = (const float*)d_in[0];
    const int*   ei = (const int*)d_in[1];
    const float* W1 = (const float*)d_in[2];
    const float* b1 = (const float*)d_in[3];
    const float* W2 = (const float*)d_in[4];
    const float* b2 = (const float*)d_in[5];
    float* out = (float*)d_out;

    const int N = in_sizes[0] / 128;
    const int E = in_sizes[1] / 2;
    const int* srcp = ei;
    const int* dstp = ei + E;

    // workspace layout (floats/ints, 4B each)
    size_t need_elems = (size_t)2 * N * 128 + N + N + (N + 1) + 1024 + (size_t)2 * (E + N);
    if (ws_size < need_elems * 4) {
        // insufficient scratch: emit zeros (diagnostic fallback)
        zero_out<<<(out_size + 255) / 256, 256, 0, stream>>>(out, out_size);
        return;
    }
    float* H1    = (float*)d_ws;                 // N*128 (reused as H2: N*64)
    float* A1    = H1 + (size_t)N * 128;         // N*128
    float* dinv  = A1 + (size_t)N * 128;         // N
    int*   cnt   = (int*)(dinv + N);             // N  (deg counts, then cursor)
    int*   rp    = cnt + N;                      // N+1
    int*   bsum  = rp + N + 1;                   // up to 1024
    int*   edata = bsum + 1024;                  // 2*(E+N) interleaved {src, norm}
    float* H2    = H1;

    hipMemsetAsync(cnt, 0, (size_t)N * sizeof(int), stream);
    hist_kernel<<<(E + 255) / 256, 256, 0, stream>>>(dstp, cnt, E);
    finalize_deg<<<(N + 255) / 256, 256, 0, stream>>>(cnt, dinv, N);
    int nb = (N + 1023) / 1024;                  // 98 for N=100000 (must be <=128)
    scan_block<<<nb, 256, 0, stream>>>(cnt, rp, bsum, N);
    scan_bsum<<<1, 128, 0, stream>>>(bsum, nb);
    scan_add<<<(N + 255) / 256, 256, 0, stream>>>(rp, bsum, N);
    cursor_init<<<(N + 255) / 256, 256, 0, stream>>>(cnt, rp, N);
    fill_edges<<<(E + 255) / 256, 256, 0, stream>>>(srcp, dstp, dinv, cnt, edata, E);
    fill_self<<<(N + 255) / 256, 256, 0, stream>>>(dinv, cnt, edata, N);

    gemm_k128<128><<<(N + 31) / 32, 256, 0, stream>>>(x, W1, H1, N);
    aggregate<128, true><<<(N + 3) / 4, 256, 0, stream>>>(H1, rp, edata, b1, A1, N);
    gemm_k128<64><<<(N + 31) / 32, 256, 0, stream>>>(A1, W2, H2, N);
    aggregate<64, false><<<(N + 3) / 4, 256, 0, stream>>>(H2, rp, edata, b2, out, N);
}

// Round 2
// 402.271 us; speedup vs baseline: 1.2639x; 1.2639x over previous
//
#include <hip/hip_runtime.h>

typedef unsigned int uint;
typedef unsigned short ushort;
typedef __attribute__((ext_vector_type(8))) short short8v;
typedef __attribute__((ext_vector_type(4))) float f32x4;

__device__ __forceinline__ ushort f2bf(float f) {
    uint u = __float_as_uint(f);
    u += 0x7fffu + ((u >> 16) & 1u);   // round-to-nearest-even
    return (ushort)(u >> 16);
}
__device__ __forceinline__ float bf2f(ushort h) {
    return __uint_as_float(((uint)h) << 16);
}

// ---------------- degree / CSR build ----------------

__global__ void hist_kernel(const int* __restrict__ dst, int* __restrict__ cnt, int E) {
    int e = blockIdx.x * 256 + threadIdx.x;
    if (e < E) atomicAdd(&cnt[dst[e]], 1);
}

__global__ void finalize_deg(int* __restrict__ cnt, float* __restrict__ dinv, int n) {
    int i = blockIdx.x * 256 + threadIdx.x;
    if (i >= n) return;
    int d = cnt[i] + 1;              // + self loop
    cnt[i] = d;
    dinv[i] = rsqrtf((float)d);
}

__global__ void scan_block(const int* __restrict__ cnt, int* __restrict__ rp,
                           int* __restrict__ bsum, int n) {
    __shared__ int s[256];
    int t = threadIdx.x;
    int base = blockIdx.x * 1024 + t * 4;
    int v0 = (base + 0 < n) ? cnt[base + 0] : 0;
    int v1 = (base + 1 < n) ? cnt[base + 1] : 0;
    int v2 = (base + 2 < n) ? cnt[base + 2] : 0;
    int v3 = (base + 3 < n) ? cnt[base + 3] : 0;
    v1 += v0; v2 += v1; v3 += v2;
    s[t] = v3;
    __syncthreads();
    for (int off = 1; off < 256; off <<= 1) {
        int tv = (t >= off) ? s[t - off] : 0;
        __syncthreads();
        s[t] += tv;
        __syncthreads();
    }
    int prefix = (t > 0) ? s[t - 1] : 0;
    if (base + 0 < n) rp[1 + base + 0] = prefix + v0;
    if (base + 1 < n) rp[1 + base + 1] = prefix + v1;
    if (base + 2 < n) rp[1 + base + 2] = prefix + v2;
    if (base + 3 < n) rp[1 + base + 3] = prefix + v3;
    if (t == 255) bsum[blockIdx.x] = s[255];
}

__global__ void scan_bsum(int* __restrict__ bsum, int nb) {
    __shared__ int s[128];
    int t = threadIdx.x;
    int v = (t < nb) ? bsum[t] : 0;
    s[t] = v;
    __syncthreads();
    for (int off = 1; off < 128; off <<= 1) {
        int tv = (t >= off) ? s[t - off] : 0;
        __syncthreads();
        s[t] += tv;
        __syncthreads();
    }
    if (t < nb) bsum[t] = (t > 0) ? s[t - 1] : 0;
}

__global__ void scan_add(int* __restrict__ rp, const int* __restrict__ bsum, int n) {
    int i = blockIdx.x * 256 + threadIdx.x;
    if (i == 0) rp[0] = 0;
    if (i < n) rp[1 + i] += bsum[i >> 10];
}

__global__ void cursor_init(int* __restrict__ cursor, const int* __restrict__ rp, int n) {
    int i = blockIdx.x * 256 + threadIdx.x;
    if (i < n) cursor[i] = rp[i];
}

__global__ void fill_edges(const int* __restrict__ src, const int* __restrict__ dst,
                           const float* __restrict__ dinv, int* __restrict__ cursor,
                           int* __restrict__ edata, int E) {
    int e = blockIdx.x * 256 + threadIdx.x;
    if (e >= E) return;
    int s = src[e], d = dst[e];
    int pos = atomicAdd(&cursor[d], 1);
    edata[2 * pos]     = s;
    edata[2 * pos + 1] = __float_as_int(dinv[s] * dinv[d]);
}

__global__ void fill_self(const float* __restrict__ dinv, int* __restrict__ cursor,
                          int* __restrict__ edata, int n) {
    int i = blockIdx.x * 256 + threadIdx.x;
    if (i >= n) return;
    int pos = atomicAdd(&cursor[i], 1);
    float w = dinv[i];
    edata[2 * pos]     = i;
    edata[2 * pos + 1] = __float_as_int(w * w);
}

// ---------------- W pre-transpose/convert/swizzle: image of [n][k] bf16, byte ^ ((n&7)<<4) ----------------

__global__ void prep_w(const float* __restrict__ W1, const float* __restrict__ W2,
                       ushort* __restrict__ Wt1s, ushort* __restrict__ Wt2s) {
    int t = blockIdx.x * 256 + threadIdx.x;
    int total = gridDim.x * 256;
    for (int idx = t; idx < 128 * 128; idx += total) {
        int nn = idx >> 7, kk = idx & 127;
        uint byte = (uint)nn * 256u + (uint)kk * 2u;
        byte ^= (uint)((nn & 7) << 4);
        Wt1s[byte >> 1] = f2bf(W1[kk * 128 + nn]);
    }
    for (int idx = t; idx < 64 * 128; idx += total) {
        int nn = idx >> 7, kk = idx & 127;
        uint byte = (uint)nn * 256u + (uint)kk * 2u;
        byte ^= (uint)((nn & 7) << 4);
        Wt2s[byte >> 1] = f2bf(W2[kk * 64 + nn]);
    }
}

// ---------------- MFMA GEMM: H[n x NCOLS] = bf16(X[n x 128]) @ W ----------------
// block = 256 threads (4 waves), 128 rows/block; wave does 32 rows (2 m-tiles) x NCOLS.
// mfma_f32_16x16x32_bf16: A row=lane&15, k=(lane>>4)*8+i ; B col=lane&15, same k ;
// D col=lane&15, row=(lane>>4)*4+reg  (verified layouts, learn_hip m89/m91/m92..m103)

template <int NCOLS, bool IN_BF16>
__launch_bounds__(256)
__global__ void gemm_mfma(const void* __restrict__ Xv, const ushort* __restrict__ Wimg,
                          ushort* __restrict__ H, int n) {
    constexpr int NT = NCOLS / 16;
    __shared__ ushort sW[NCOLS * 128];
    {
        const uint4* src = (const uint4*)Wimg;
        uint4* dst = (uint4*)sW;
        constexpr int NV = NCOLS * 128 * 2 / 16;
        for (int i = threadIdx.x; i < NV; i += 256) dst[i] = src[i];
    }
    __syncthreads();

    const int w  = threadIdx.x >> 6;
    const int l  = threadIdx.x & 63;
    const int lm = l & 15, lk = l >> 4;
    const int row_base = blockIdx.x * 128 + w * 32;

    f32x4 acc[2][NT];
#pragma unroll
    for (int mt = 0; mt < 2; ++mt)
#pragma unroll
        for (int nt = 0; nt < NT; ++nt) {
            f32x4 z = {0.f, 0.f, 0.f, 0.f};
            acc[mt][nt] = z;
        }

    int r0 = row_base + lm;
    int r1 = row_base + 16 + lm;
    int r0c = r0 < n ? r0 : n - 1;
    int r1c = r1 < n ? r1 : n - 1;

#pragma unroll
    for (int kb = 0; kb < 4; ++kb) {
        short8v a0, a1;
        if constexpr (IN_BF16) {
            const ushort* X = (const ushort*)Xv;
            a0 = *(const short8v*)(X + (size_t)r0c * 128 + kb * 32 + lk * 8);
            a1 = *(const short8v*)(X + (size_t)r1c * 128 + kb * 32 + lk * 8);
        } else {
            const float* X = (const float*)Xv;
            const float* p0 = X + (size_t)r0c * 128 + kb * 32 + lk * 8;
            const float* p1 = X + (size_t)r1c * 128 + kb * 32 + lk * 8;
            float4 u0 = *(const float4*)p0;
            float4 v0 = *(const float4*)(p0 + 4);
            float4 u1 = *(const float4*)p1;
            float4 v1 = *(const float4*)(p1 + 4);
            a0[0] = (short)f2bf(u0.x); a0[1] = (short)f2bf(u0.y);
            a0[2] = (short)f2bf(u0.z); a0[3] = (short)f2bf(u0.w);
            a0[4] = (short)f2bf(v0.x); a0[5] = (short)f2bf(v0.y);
            a0[6] = (short)f2bf(v0.z); a0[7] = (short)f2bf(v0.w);
            a1[0] = (short)f2bf(u1.x); a1[1] = (short)f2bf(u1.y);
            a1[2] = (short)f2bf(u1.z); a1[3] = (short)f2bf(u1.w);
            a1[4] = (short)f2bf(v1.x); a1[5] = (short)f2bf(v1.y);
            a1[6] = (short)f2bf(v1.z); a1[7] = (short)f2bf(v1.w);
        }
#pragma unroll
        for (int nt = 0; nt < NT; ++nt) {
            int nn = nt * 16 + lm;
            uint byte = (uint)nn * 256u + (uint)kb * 64u + (uint)lk * 16u;
            byte ^= (uint)((nn & 7) << 4);
            short8v b = *(const short8v*)((const char*)sW + byte);
            acc[0][nt] = __builtin_amdgcn_mfma_f32_16x16x32_bf16(a0, b, acc[0][nt], 0, 0, 0);
            acc[1][nt] = __builtin_amdgcn_mfma_f32_16x16x32_bf16(a1, b, acc[1][nt], 0, 0, 0);
        }
    }

#pragma unroll
    for (int mt = 0; mt < 2; ++mt)
#pragma unroll
        for (int nt = 0; nt < NT; ++nt)
#pragma unroll
            for (int r = 0; r < 4; ++r) {
                int row = row_base + mt * 16 + lk * 4 + r;
                if (row < n) H[(size_t)row * NCOLS + nt * 16 + lm] = f2bf(acc[mt][nt][r]);
            }
}

// ---------------- aggregation (bf16 gather) ----------------

template <bool RELU>
__launch_bounds__(256)
__global__ void agg128(const ushort* __restrict__ H, const int* __restrict__ rp,
                       const int* __restrict__ edata, const float* __restrict__ bias,
                       ushort* __restrict__ out, int n) {
    int gw = (blockIdx.x * 256 + threadIdx.x) >> 6;
    int lane = threadIdx.x & 63;
    if (gw >= n) return;
    int e = rp[gw], end = rp[gw + 1];
    int u = lane * 2;
    float ax = 0.f, ay = 0.f;
    for (; e + 2 <= end; e += 2) {
        int2 m0 = *(const int2*)&edata[2 * e];
        int2 m1 = *(const int2*)&edata[2 * e + 2];
        uint h0 = *(const uint*)&H[(size_t)m0.x * 128 + u];
        uint h1 = *(const uint*)&H[(size_t)m1.x * 128 + u];
        float w0 = __int_as_float(m0.y), w1 = __int_as_float(m1.y);
        ax += w0 * bf2f((ushort)h0); ay += w0 * bf2f((ushort)(h0 >> 16));
        ax += w1 * bf2f((ushort)h1); ay += w1 * bf2f((ushort)(h1 >> 16));
    }
    if (e < end) {
        int2 m = *(const int2*)&edata[2 * e];
        uint h = *(const uint*)&H[(size_t)m.x * 128 + u];
        float w = __int_as_float(m.y);
        ax += w * bf2f((ushort)h); ay += w * bf2f((ushort)(h >> 16));
    }
    ax += bias[u]; ay += bias[u + 1];
    if (RELU) { ax = fmaxf(ax, 0.f); ay = fmaxf(ay, 0.f); }
    uint packed = (uint)f2bf(ax) | ((uint)f2bf(ay) << 16);
    *(uint*)&out[(size_t)gw * 128 + u] = packed;
}

// D=64 final layer: two edges per wave (lanes 0-31 edge e, 32-63 edge e+1), fp32 out.
__launch_bounds__(256)
__global__ void agg64(const ushort* __restrict__ H, const int* __restrict__ rp,
                      const int* __restrict__ edata, const float* __restrict__ bias,
                      float* __restrict__ out, int n) {
    int gw = (blockIdx.x * 256 + threadIdx.x) >> 6;
    int lane = threadIdx.x & 63;
    if (gw >= n) return;
    int half = lane >> 5, c = lane & 31;
    int u = c * 2;
    int e = rp[gw], end = rp[gw + 1];
    float ax = 0.f, ay = 0.f;
    int i = e;
    for (; i + 2 <= end; i += 2) {
        int2 m = *(const int2*)&edata[2 * (i + half)];
        uint h = *(const uint*)&H[(size_t)m.x * 64 + u];
        float w = __int_as_float(m.y);
        ax += w * bf2f((ushort)h); ay += w * bf2f((ushort)(h >> 16));
    }
    if (i < end && half == 0) {
        int2 m = *(const int2*)&edata[2 * i];
        uint h = *(const uint*)&H[(size_t)m.x * 64 + u];
        float w = __int_as_float(m.y);
        ax += w * bf2f((ushort)h); ay += w * bf2f((ushort)(h >> 16));
    }
    ax += __shfl_xor(ax, 32);
    ay += __shfl_xor(ay, 32);
    if (half == 0) {
        ax += bias[u]; ay += bias[u + 1];
        *(float2*)&out[(size_t)gw * 64 + u] = make_float2(ax, ay);
    }
}

__global__ void zero_out(float* __restrict__ out, int n) {
    int i = blockIdx.x * 256 + threadIdx.x;
    if (i < n) out[i] = 0.f;
}

// ---------------- launch ----------------

extern "C" void kernel_launch(void* const* d_in, const int* in_sizes, int n_in,
                              void* d_out, int out_size, void* d_ws, size_t ws_size,
                              hipStream_t stream) {
    const float* x  = (const float*)d_in[0];
    const int*   ei = (const int*)d_in[1];
    const float* W1 = (const float*)d_in[2];
    const float* b1 = (const float*)d_in[3];
    const float* W2 = (const float*)d_in[4];
    const float* b2 = (const float*)d_in[5];
    float* out = (float*)d_out;

    const int N = in_sizes[0] / 128;
    const int E = in_sizes[1] / 2;
    const int* srcp = ei;
    const int* dstp = ei + E;

    char* base = (char*)d_ws;
    size_t off = 0;
    auto alloc = [&](size_t bytes) -> void* {
        void* p = base + off;
        off += (bytes + 15) & ~(size_t)15;
        return p;
    };
    ushort* H1   = (ushort*)alloc((size_t)N * 128 * 2);
    ushort* A1   = (ushort*)alloc((size_t)N * 128 * 2);
    ushort* Wt1s = (ushort*)alloc(128 * 128 * 2);
    ushort* Wt2s = (ushort*)alloc(64 * 128 * 2);
    float*  dinv = (float*)alloc((size_t)N * 4);
    int*    cnt  = (int*)alloc((size_t)N * 4);
    int*    rp   = (int*)alloc((size_t)(N + 1) * 4);
    int*    bsum = (int*)alloc(1024 * 4);
    int*    edata= (int*)alloc((size_t)2 * (E + N) * 4);
    ushort* H2   = H1;   // reuse layer-1 buffer

    if (off > ws_size) {
        zero_out<<<(out_size + 255) / 256, 256, 0, stream>>>(out, out_size);
        return;
    }

    hipMemsetAsync(cnt, 0, (size_t)N * sizeof(int), stream);
    hist_kernel<<<(E + 255) / 256, 256, 0, stream>>>(dstp, cnt, E);
    finalize_deg<<<(N + 255) / 256, 256, 0, stream>>>(cnt, dinv, N);
    int nb = (N + 1023) / 1024;
    scan_block<<<nb, 256, 0, stream>>>(cnt, rp, bsum, N);
    scan_bsum<<<1, 128, 0, stream>>>(bsum, nb);
    scan_add<<<(N + 255) / 256, 256, 0, stream>>>(rp, bsum, N);
    cursor_init<<<(N + 255) / 256, 256, 0, stream>>>(cnt, rp, N);
    fill_edges<<<(E + 255) / 256, 256, 0, stream>>>(srcp, dstp, dinv, cnt, edata, E);
    fill_self<<<(N + 255) / 256, 256, 0, stream>>>(dinv, cnt, edata, N);
    prep_w<<<32, 256, 0, stream>>>(W1, W2, Wt1s, Wt2s);

    gemm_mfma<128, false><<<(N + 127) / 128, 256, 0, stream>>>(x, Wt1s, H1, N);
    agg128<true><<<(N + 3) / 4, 256, 0, stream>>>(H1, rp, edata, b1, A1, N);
    gemm_mfma<64, true><<<(N + 127) / 128, 256, 0, stream>>>(A1, Wt2s, H2, N);
    agg64<<<(N + 3) / 4, 256, 0, stream>>>(H2, rp, edata, b2, out, N);
}

// Round 3
// 339.798 us; speedup vs baseline: 1.4963x; 1.1839x over previous
//
#include <hip/hip_runtime.h>

typedef unsigned int uint;
typedef unsigned short ushort;
typedef __attribute__((ext_vector_type(8))) short short8v;
typedef __attribute__((ext_vector_type(4))) float f32x4;

__device__ __forceinline__ ushort f2bf(float f) {
    uint u = __float_as_uint(f);
    u += 0x7fffu + ((u >> 16) & 1u);   // round-to-nearest-even
    return (ushort)(u >> 16);
}
__device__ __forceinline__ float bf2f(ushort h) {
    return __uint_as_float(((uint)h) << 16);
}

// ---------------- degree / CSR build ----------------

__global__ void hist_kernel(const int* __restrict__ dst, int* __restrict__ cnt, int E) {
    int i = (blockIdx.x * 256 + threadIdx.x) * 4;
    if (i + 4 <= E) {
        int4 d = *(const int4*)&dst[i];
        atomicAdd(&cnt[d.x], 1);
        atomicAdd(&cnt[d.y], 1);
        atomicAdd(&cnt[d.z], 1);
        atomicAdd(&cnt[d.w], 1);
    } else {
        for (int k = i; k < E; ++k) atomicAdd(&cnt[dst[k]], 1);
    }
}

__global__ void finalize_deg(int* __restrict__ cnt, float* __restrict__ dinv, int n) {
    int i = blockIdx.x * 256 + threadIdx.x;
    if (i >= n) return;
    int d = cnt[i] + 1;              // + self loop
    cnt[i] = d;
    dinv[i] = rsqrtf((float)d);
}

__global__ void scan_block(const int* __restrict__ cnt, int* __restrict__ rp,
                           int* __restrict__ bsum, int n) {
    __shared__ int s[256];
    int t = threadIdx.x;
    int base = blockIdx.x * 1024 + t * 4;
    int v0 = (base + 0 < n) ? cnt[base + 0] : 0;
    int v1 = (base + 1 < n) ? cnt[base + 1] : 0;
    int v2 = (base + 2 < n) ? cnt[base + 2] : 0;
    int v3 = (base + 3 < n) ? cnt[base + 3] : 0;
    v1 += v0; v2 += v1; v3 += v2;
    s[t] = v3;
    __syncthreads();
    for (int off = 1; off < 256; off <<= 1) {
        int tv = (t >= off) ? s[t - off] : 0;
        __syncthreads();
        s[t] += tv;
        __syncthreads();
    }
    int prefix = (t > 0) ? s[t - 1] : 0;
    if (base + 0 < n) rp[1 + base + 0] = prefix + v0;
    if (base + 1 < n) rp[1 + base + 1] = prefix + v1;
    if (base + 2 < n) rp[1 + base + 2] = prefix + v2;
    if (base + 3 < n) rp[1 + base + 3] = prefix + v3;
    if (t == 255) bsum[blockIdx.x] = s[255];
}

__global__ void scan_bsum(int* __restrict__ bsum, int nb) {
    __shared__ int s[128];
    int t = threadIdx.x;
    int v = (t < nb) ? bsum[t] : 0;
    s[t] = v;
    __syncthreads();
    for (int off = 1; off < 128; off <<= 1) {
        int tv = (t >= off) ? s[t - off] : 0;
        __syncthreads();
        s[t] += tv;
        __syncthreads();
    }
    if (t < nb) bsum[t] = (t > 0) ? s[t - 1] : 0;
}

// writes final rp AND initializes cursor (= rp) in one pass
__global__ void scan_add(int* __restrict__ rp, const int* __restrict__ bsum,
                         int* __restrict__ cursor, int n) {
    int i = blockIdx.x * 256 + threadIdx.x;
    if (i == 0) { rp[0] = 0; cursor[0] = 0; }
    if (i < n) {
        int v = rp[1 + i] + bsum[i >> 10];
        rp[1 + i] = v;
        if (i + 1 < n) cursor[i + 1] = v;
    }
}

__global__ void fill_edges(const int* __restrict__ src, const int* __restrict__ dst,
                           const float* __restrict__ dinv, int* __restrict__ cursor,
                           int* __restrict__ edata, int E) {
    int e = blockIdx.x * 256 + threadIdx.x;
    if (e >= E) return;
    int s = src[e], d = dst[e];
    int pos = atomicAdd(&cursor[d], 1);
    *(int2*)&edata[2 * pos] = make_int2(s, __float_as_int(dinv[s] * dinv[d]));
}

__global__ void fill_self(const float* __restrict__ dinv, int* __restrict__ cursor,
                          int* __restrict__ edata, int n) {
    int i = blockIdx.x * 256 + threadIdx.x;
    if (i >= n) return;
    int pos = atomicAdd(&cursor[i], 1);
    float w = dinv[i];
    *(int2*)&edata[2 * pos] = make_int2(i, __float_as_int(w * w));
}

// ---------------- W pre-transpose/convert/swizzle: image of [n][k] bf16, byte ^ ((n&7)<<4) ----------------

__global__ void prep_w(const float* __restrict__ W1, const float* __restrict__ W2,
                       ushort* __restrict__ Wt1s, ushort* __restrict__ Wt2s) {
    int t = blockIdx.x * 256 + threadIdx.x;
    int total = gridDim.x * 256;
    for (int idx = t; idx < 128 * 128; idx += total) {
        int nn = idx >> 7, kk = idx & 127;
        uint byte = (uint)nn * 256u + (uint)kk * 2u;
        byte ^= (uint)((nn & 7) << 4);
        Wt1s[byte >> 1] = f2bf(W1[kk * 128 + nn]);
    }
    for (int idx = t; idx < 64 * 128; idx += total) {
        int nn = idx >> 7, kk = idx & 127;
        uint byte = (uint)nn * 256u + (uint)kk * 2u;
        byte ^= (uint)((nn & 7) << 4);
        Wt2s[byte >> 1] = f2bf(W2[kk * 64 + nn]);
    }
}

// ---------------- MFMA GEMM: H[n x NCOLS] = bf16(X[n x 128]) @ W ----------------
// mfma_f32_16x16x32_bf16: A row=lane&15, k=(lane>>4)*8+i ; B col=lane&15, same k ;
// D col=lane&15, row=(lane>>4)*4+reg

template <int NCOLS, bool IN_BF16>
__launch_bounds__(256)
__global__ void gemm_mfma(const void* __restrict__ Xv, const ushort* __restrict__ Wimg,
                          ushort* __restrict__ H, int n) {
    constexpr int NT = NCOLS / 16;
    __shared__ ushort sW[NCOLS * 128];
    {
        const uint4* src = (const uint4*)Wimg;
        uint4* dst = (uint4*)sW;
        constexpr int NV = NCOLS * 128 * 2 / 16;
        for (int i = threadIdx.x; i < NV; i += 256) dst[i] = src[i];
    }
    __syncthreads();

    const int w  = threadIdx.x >> 6;
    const int l  = threadIdx.x & 63;
    const int lm = l & 15, lk = l >> 4;
    const int row_base = blockIdx.x * 128 + w * 32;

    f32x4 acc[2][NT];
#pragma unroll
    for (int mt = 0; mt < 2; ++mt)
#pragma unroll
        for (int nt = 0; nt < NT; ++nt) {
            f32x4 z = {0.f, 0.f, 0.f, 0.f};
            acc[mt][nt] = z;
        }

    int r0 = row_base + lm;
    int r1 = row_base + 16 + lm;
    int r0c = r0 < n ? r0 : n - 1;
    int r1c = r1 < n ? r1 : n - 1;

#pragma unroll
    for (int kb = 0; kb < 4; ++kb) {
        short8v a0, a1;
        if constexpr (IN_BF16) {
            const ushort* X = (const ushort*)Xv;
            a0 = *(const short8v*)(X + (size_t)r0c * 128 + kb * 32 + lk * 8);
            a1 = *(const short8v*)(X + (size_t)r1c * 128 + kb * 32 + lk * 8);
        } else {
            const float* X = (const float*)Xv;
            const float* p0 = X + (size_t)r0c * 128 + kb * 32 + lk * 8;
            const float* p1 = X + (size_t)r1c * 128 + kb * 32 + lk * 8;
            float4 u0 = *(const float4*)p0;
            float4 v0 = *(const float4*)(p0 + 4);
            float4 u1 = *(const float4*)p1;
            float4 v1 = *(const float4*)(p1 + 4);
            a0[0] = (short)f2bf(u0.x); a0[1] = (short)f2bf(u0.y);
            a0[2] = (short)f2bf(u0.z); a0[3] = (short)f2bf(u0.w);
            a0[4] = (short)f2bf(v0.x); a0[5] = (short)f2bf(v0.y);
            a0[6] = (short)f2bf(v0.z); a0[7] = (short)f2bf(v0.w);
            a1[0] = (short)f2bf(u1.x); a1[1] = (short)f2bf(u1.y);
            a1[2] = (short)f2bf(u1.z); a1[3] = (short)f2bf(u1.w);
            a1[4] = (short)f2bf(v1.x); a1[5] = (short)f2bf(v1.y);
            a1[6] = (short)f2bf(v1.z); a1[7] = (short)f2bf(v1.w);
        }
#pragma unroll
        for (int nt = 0; nt < NT; ++nt) {
            int nn = nt * 16 + lm;
            uint byte = (uint)nn * 256u + (uint)kb * 64u + (uint)lk * 16u;
            byte ^= (uint)((nn & 7) << 4);
            short8v b = *(const short8v*)((const char*)sW + byte);
            acc[0][nt] = __builtin_amdgcn_mfma_f32_16x16x32_bf16(a0, b, acc[0][nt], 0, 0, 0);
            acc[1][nt] = __builtin_amdgcn_mfma_f32_16x16x32_bf16(a1, b, acc[1][nt], 0, 0, 0);
        }
    }

#pragma unroll
    for (int mt = 0; mt < 2; ++mt)
#pragma unroll
        for (int nt = 0; nt < NT; ++nt)
#pragma unroll
            for (int r = 0; r < 4; ++r) {
                int row = row_base + mt * 16 + lk * 4 + r;
                if (row < n) H[(size_t)row * NCOLS + nt * 16 + lm] = f2bf(acc[mt][nt][r]);
            }
}

// ---------------- aggregation (bf16 gather, MLP-maximized) ----------------
// agg128: wave per node; 32 lanes x uint2 (4 bf16) per edge; 2 edges per load instr;
// metadata batch-loaded 16 edges at a time and shfl-broadcast -> 8 gathers in flight.

template <bool RELU>
__launch_bounds__(256)
__global__ void agg128(const ushort* __restrict__ H, const int* __restrict__ rp,
                       const int* __restrict__ edata, const float* __restrict__ bias,
                       ushort* __restrict__ out, int n) {
    int gw = (blockIdx.x * 256 + threadIdx.x) >> 6;
    int lane = threadIdx.x & 63;
    if (gw >= n) return;
    const int h = lane >> 5, c = lane & 31;
    int e = rp[gw], end = rp[gw + 1];
    float a0 = 0.f, a1 = 0.f, a2 = 0.f, a3 = 0.f;

    while (e + 16 <= end) {
        int2 md = make_int2(0, 0);
        if (lane < 16) md = *(const int2*)&edata[2 * (e + lane)];
#pragma unroll
        for (int j = 0; j < 8; ++j) {
            int   si = __shfl(md.x, 2 * j + h);
            float w  = __int_as_float(__shfl(md.y, 2 * j + h));
            uint2 hv = *(const uint2*)&H[(size_t)si * 128 + c * 4];
            a0 += w * bf2f((ushort)hv.x); a1 += w * bf2f((ushort)(hv.x >> 16));
            a2 += w * bf2f((ushort)hv.y); a3 += w * bf2f((ushort)(hv.y >> 16));
        }
        e += 16;
    }
    while (e + 2 <= end) {
        int2 md = *(const int2*)&edata[2 * (e + h)];
        float w = __int_as_float(md.y);
        uint2 hv = *(const uint2*)&H[(size_t)md.x * 128 + c * 4];
        a0 += w * bf2f((ushort)hv.x); a1 += w * bf2f((ushort)(hv.x >> 16));
        a2 += w * bf2f((ushort)hv.y); a3 += w * bf2f((ushort)(hv.y >> 16));
        e += 2;
    }
    if (e < end && h == 0) {
        int2 md = *(const int2*)&edata[2 * e];
        float w = __int_as_float(md.y);
        uint2 hv = *(const uint2*)&H[(size_t)md.x * 128 + c * 4];
        a0 += w * bf2f((ushort)hv.x); a1 += w * bf2f((ushort)(hv.x >> 16));
        a2 += w * bf2f((ushort)hv.y); a3 += w * bf2f((ushort)(hv.y >> 16));
    }
    a0 += __shfl_xor(a0, 32); a1 += __shfl_xor(a1, 32);
    a2 += __shfl_xor(a2, 32); a3 += __shfl_xor(a3, 32);
    if (h == 0) {
        a0 += bias[c * 4 + 0]; a1 += bias[c * 4 + 1];
        a2 += bias[c * 4 + 2]; a3 += bias[c * 4 + 3];
        if (RELU) {
            a0 = fmaxf(a0, 0.f); a1 = fmaxf(a1, 0.f);
            a2 = fmaxf(a2, 0.f); a3 = fmaxf(a3, 0.f);
        }
        uint2 pk;
        pk.x = (uint)f2bf(a0) | ((uint)f2bf(a1) << 16);
        pk.y = (uint)f2bf(a2) | ((uint)f2bf(a3) << 16);
        *(uint2*)&out[(size_t)gw * 128 + c * 4] = pk;
    }
}

// agg64: 16 lanes x uint2 per edge; 4 edges per load instr; 16-edge metadata batches.
__launch_bounds__(256)
__global__ void agg64(const ushort* __restrict__ H, const int* __restrict__ rp,
                      const int* __restrict__ edata, const float* __restrict__ bias,
                      float* __restrict__ out, int n) {
    int gw = (blockIdx.x * 256 + threadIdx.x) >> 6;
    int lane = threadIdx.x & 63;
    if (gw >= n) return;
    const int q = lane >> 4, c = lane & 15;
    int e = rp[gw], end = rp[gw + 1];
    float a0 = 0.f, a1 = 0.f, a2 = 0.f, a3 = 0.f;

    while (e + 16 <= end) {
        int2 md = make_int2(0, 0);
        if (lane < 16) md = *(const int2*)&edata[2 * (e + lane)];
#pragma unroll
        for (int j = 0; j < 4; ++j) {
            int   si = __shfl(md.x, 4 * j + q);
            float w  = __int_as_float(__shfl(md.y, 4 * j + q));
            uint2 hv = *(const uint2*)&H[(size_t)si * 64 + c * 4];
            a0 += w * bf2f((ushort)hv.x); a1 += w * bf2f((ushort)(hv.x >> 16));
            a2 += w * bf2f((ushort)hv.y); a3 += w * bf2f((ushort)(hv.y >> 16));
        }
        e += 16;
    }
    while (e + 4 <= end) {
        int2 md = *(const int2*)&edata[2 * (e + q)];
        float w = __int_as_float(md.y);
        uint2 hv = *(const uint2*)&H[(size_t)md.x * 64 + c * 4];
        a0 += w * bf2f((ushort)hv.x); a1 += w * bf2f((ushort)(hv.x >> 16));
        a2 += w * bf2f((ushort)hv.y); a3 += w * bf2f((ushort)(hv.y >> 16));
        e += 4;
    }
    int rem = end - e;
    if (q < rem) {
        int2 md = *(const int2*)&edata[2 * (e + q)];
        float w = __int_as_float(md.y);
        uint2 hv = *(const uint2*)&H[(size_t)md.x * 64 + c * 4];
        a0 += w * bf2f((ushort)hv.x); a1 += w * bf2f((ushort)(hv.x >> 16));
        a2 += w * bf2f((ushort)hv.y); a3 += w * bf2f((ushort)(hv.y >> 16));
    }
    a0 += __shfl_xor(a0, 16); a0 += __shfl_xor(a0, 32);
    a1 += __shfl_xor(a1, 16); a1 += __shfl_xor(a1, 32);
    a2 += __shfl_xor(a2, 16); a2 += __shfl_xor(a2, 32);
    a3 += __shfl_xor(a3, 16); a3 += __shfl_xor(a3, 32);
    if (q == 0) {
        a0 += bias[c * 4 + 0]; a1 += bias[c * 4 + 1];
        a2 += bias[c * 4 + 2]; a3 += bias[c * 4 + 3];
        *(float4*)&out[(size_t)gw * 64 + c * 4] = make_float4(a0, a1, a2, a3);
    }
}

__global__ void zero_out(float* __restrict__ out, int n) {
    int i = blockIdx.x * 256 + threadIdx.x;
    if (i < n) out[i] = 0.f;
}

// ---------------- launch ----------------

extern "C" void kernel_launch(void* const* d_in, const int* in_sizes, int n_in,
                              void* d_out, int out_size, void* d_ws, size_t ws_size,
                              hipStream_t stream) {
    const float* x  = (const float*)d_in[0];
    const int*   ei = (const int*)d_in[1];
    const float* W1 = (const float*)d_in[2];
    const float* b1 = (const float*)d_in[3];
    const float* W2 = (const float*)d_in[4];
    const float* b2 = (const float*)d_in[5];
    float* out = (float*)d_out;

    const int N = in_sizes[0] / 128;
    const int E = in_sizes[1] / 2;
    const int* srcp = ei;
    const int* dstp = ei + E;

    char* base = (char*)d_ws;
    size_t off = 0;
    auto alloc = [&](size_t bytes) -> void* {
        void* p = base + off;
        off += (bytes + 15) & ~(size_t)15;
        return p;
    };
    ushort* H1   = (ushort*)alloc((size_t)N * 128 * 2);
    ushort* A1   = (ushort*)alloc((size_t)N * 128 * 2);
    ushort* Wt1s = (ushort*)alloc(128 * 128 * 2);
    ushort* Wt2s = (ushort*)alloc(64 * 128 * 2);
    float*  dinv = (float*)alloc((size_t)N * 4);
    int*    cnt  = (int*)alloc((size_t)N * 4);
    int*    rp   = (int*)alloc((size_t)(N + 1) * 4);
    int*    bsum = (int*)alloc(1024 * 4);
    int*    edata= (int*)alloc((size_t)2 * (E + N) * 4);
    ushort* H2   = H1;   // reuse layer-1 buffer

    if (off > ws_size) {
        zero_out<<<(out_size + 255) / 256, 256, 0, stream>>>(out, out_size);
        return;
    }

    hipMemsetAsync(cnt, 0, (size_t)N * sizeof(int), stream);
    hist_kernel<<<(E / 4 + 255) / 256, 256, 0, stream>>>(dstp, cnt, E);
    finalize_deg<<<(N + 255) / 256, 256, 0, stream>>>(cnt, dinv, N);
    int nb = (N + 1023) / 1024;
    scan_block<<<nb, 256, 0, stream>>>(cnt, rp, bsum, N);
    scan_bsum<<<1, 128, 0, stream>>>(bsum, nb);
    scan_add<<<(N + 255) / 256, 256, 0, stream>>>(rp, bsum, cnt, N);  // cnt becomes cursor
    fill_edges<<<(E + 255) / 256, 256, 0, stream>>>(srcp, dstp, dinv, cnt, edata, E);
    fill_self<<<(N + 255) / 256, 256, 0, stream>>>(dinv, cnt, edata, N);
    prep_w<<<32, 256, 0, stream>>>(W1, W2, Wt1s, Wt2s);

    gemm_mfma<128, false><<<(N + 127) / 128, 256, 0, stream>>>(x, Wt1s, H1, N);
    agg128<true><<<(N + 3) / 4, 256, 0, stream>>>(H1, rp, edata, b1, A1, N);
    gemm_mfma<64, true><<<(N + 127) / 128, 256, 0, stream>>>(A1, Wt2s, H2, N);
    agg64<<<(N + 3) / 4, 256, 0, stream>>>(H2, rp, edata, b2, out, N);
}

// Round 4
// 327.798 us; speedup vs baseline: 1.5511x; 1.0366x over previous
//
#include <hip/hip_runtime.h>

typedef unsigned int uint;
typedef unsigned short ushort;
typedef __attribute__((ext_vector_type(8))) short short8v;
typedef __attribute__((ext_vector_type(4))) float f32x4;

#define MAXB 64   // max coarse buckets (LDS-array bound)

__device__ __forceinline__ ushort f2bf(float f) {
    uint u = __float_as_uint(f);
    u += 0x7fffu + ((u >> 16) & 1u);   // round-to-nearest-even
    return (ushort)(u >> 16);
}
__device__ __forceinline__ float bf2f(ushort h) {
    return __uint_as_float(((uint)h) << 16);
}

// ---------------- degree ----------------

__global__ void hist_kernel(const int* __restrict__ dst, int* __restrict__ cnt, int E) {
    int i = (blockIdx.x * 256 + threadIdx.x) * 4;
    if (i + 4 <= E) {
        int4 d = *(const int4*)&dst[i];
        atomicAdd(&cnt[d.x], 1);
        atomicAdd(&cnt[d.y], 1);
        atomicAdd(&cnt[d.z], 1);
        atomicAdd(&cnt[d.w], 1);
    } else {
        for (int k = i; k < E; ++k) atomicAdd(&cnt[dst[k]], 1);
    }
}

__global__ void finalize_deg(int* __restrict__ cnt, float* __restrict__ dinv, int n) {
    int i = blockIdx.x * 256 + threadIdx.x;
    if (i >= n) return;
    int d = cnt[i] + 1;              // + self loop
    cnt[i] = d;
    dinv[i] = rsqrtf((float)d);
}

// ---------------- rp prefix scan ----------------

__global__ void scan_block(const int* __restrict__ cnt, int* __restrict__ rp,
                           int* __restrict__ bsum, int n) {
    __shared__ int s[256];
    int t = threadIdx.x;
    int base = blockIdx.x * 1024 + t * 4;
    int v0 = (base + 0 < n) ? cnt[base + 0] : 0;
    int v1 = (base + 1 < n) ? cnt[base + 1] : 0;
    int v2 = (base + 2 < n) ? cnt[base + 2] : 0;
    int v3 = (base + 3 < n) ? cnt[base + 3] : 0;
    v1 += v0; v2 += v1; v3 += v2;
    s[t] = v3;
    __syncthreads();
    for (int off = 1; off < 256; off <<= 1) {
        int tv = (t >= off) ? s[t - off] : 0;
        __syncthreads();
        s[t] += tv;
        __syncthreads();
    }
    int prefix = (t > 0) ? s[t - 1] : 0;
    if (base + 0 < n) rp[1 + base + 0] = prefix + v0;
    if (base + 1 < n) rp[1 + base + 1] = prefix + v1;
    if (base + 2 < n) rp[1 + base + 2] = prefix + v2;
    if (base + 3 < n) rp[1 + base + 3] = prefix + v3;
    if (t == 255) bsum[blockIdx.x] = s[255];
}

__global__ void scan_bsum(int* __restrict__ bsum, int nb) {
    __shared__ int s[128];
    int t = threadIdx.x;
    int v = (t < nb) ? bsum[t] : 0;
    s[t] = v;
    __syncthreads();
    for (int off = 1; off < 128; off <<= 1) {
        int tv = (t >= off) ? s[t - off] : 0;
        __syncthreads();
        s[t] += tv;
        __syncthreads();
    }
    if (t < nb) bsum[t] = (t > 0) ? s[t - 1] : 0;
}

// writes final rp AND initializes cursor (= rp) in one pass
__global__ void scan_add(int* __restrict__ rp, const int* __restrict__ bsum,
                         int* __restrict__ cursor, int n) {
    int i = blockIdx.x * 256 + threadIdx.x;
    if (i == 0) { rp[0] = 0; cursor[0] = 0; }
    if (i < n) {
        int v = rp[1 + i] + bsum[i >> 10];
        rp[1 + i] = v;
        if (i + 1 < n) cursor[i + 1] = v;
    }
}

// ---------------- two-pass binned CSR fill ----------------
// Pass A: bin edges by coarse bucket (dst>>shift, <=MAXB buckets) with dense writes.

__global__ void bucket_hist(const int* __restrict__ dst, int* __restrict__ bcnt,
                            int E, int shift) {
    __shared__ int s[MAXB];
    int t = threadIdx.x;
    if (t < MAXB) s[t] = 0;
    __syncthreads();
    int i0 = blockIdx.x * 4096 + t;
#pragma unroll
    for (int k = 0; k < 16; ++k) {
        int i = i0 + k * 256;
        if (i < E) atomicAdd(&s[dst[i] >> shift], 1);
    }
    __syncthreads();
    if (t < MAXB && s[t] > 0) atomicAdd(&bcnt[t], s[t]);
}

// single wave: exclusive scan of bcnt -> bcur
__global__ void bucket_scan(const int* __restrict__ bcnt, int* __restrict__ bcur, int nb) {
    int t = threadIdx.x;            // 64 threads
    int v = (t < nb) ? bcnt[t] : 0;
    int incl = v;
    for (int o = 1; o < 64; o <<= 1) {
        int u = __shfl_up(incl, o);
        if (t >= o) incl += u;
    }
    if (t < nb) bcur[t] = incl - v;
}

__global__ void bucket_scatter(const int* __restrict__ src, const int* __restrict__ dst,
                               const float* __restrict__ dinv, int* __restrict__ bcur,
                               int2* __restrict__ tsw, int* __restrict__ tdst,
                               int E, int shift) {
    __shared__ int cnt[MAXB];
    __shared__ int base[MAXB];
    int t = threadIdx.x;
    if (t < MAXB) cnt[t] = 0;
    __syncthreads();
    int i0 = blockIdx.x * 4096 + t;
    int s_[16], d_[16], r_[16];
    float w_[16];
#pragma unroll
    for (int k = 0; k < 16; ++k) {
        int i = i0 + k * 256;
        if (i < E) {
            int s = src[i], d = dst[i];
            s_[k] = s; d_[k] = d;
            w_[k] = dinv[s] * dinv[d];
            r_[k] = atomicAdd(&cnt[d >> shift], 1);
        } else {
            d_[k] = -1;
        }
    }
    __syncthreads();
    if (t < MAXB && cnt[t] > 0) base[t] = atomicAdd(&bcur[t], cnt[t]);
    __syncthreads();
#pragma unroll
    for (int k = 0; k < 16; ++k) {
        if (d_[k] >= 0) {
            int p = base[d_[k] >> shift] + r_[k];
            tsw[p]  = make_int2(s_[k], __float_as_int(w_[k]));
            tdst[p] = d_[k];
        }
    }
}

// Pass B: stream bucketed records; scatter confined to one coarse-bucket CSR window (L2-local)
__global__ void fill_final(const int2* __restrict__ tsw, const int* __restrict__ tdst,
                           int* __restrict__ cursor, int2* __restrict__ edata, int E) {
    int i = blockIdx.x * 256 + threadIdx.x;
    if (i >= E) return;
    int d = tdst[i];
    int pos = atomicAdd(&cursor[d], 1);
    edata[pos] = tsw[i];
}

__global__ void fill_self(const float* __restrict__ dinv, int* __restrict__ cursor,
                          int2* __restrict__ edata, int n) {
    int i = blockIdx.x * 256 + threadIdx.x;
    if (i >= n) return;
    int pos = atomicAdd(&cursor[i], 1);
    float w = dinv[i];
    edata[pos] = make_int2(i, __float_as_int(w * w));
}

// ---------------- W pre-transpose/convert/swizzle: [n][k] bf16 image, byte ^ ((n&7)<<4) ----------------

__global__ void prep_w(const float* __restrict__ W1, const float* __restrict__ W2,
                       ushort* __restrict__ Wt1s, ushort* __restrict__ Wt2s) {
    int t = blockIdx.x * 256 + threadIdx.x;
    int total = gridDim.x * 256;
    for (int idx = t; idx < 128 * 128; idx += total) {
        int nn = idx >> 7, kk = idx & 127;
        uint byte = (uint)nn * 256u + (uint)kk * 2u;
        byte ^= (uint)((nn & 7) << 4);
        Wt1s[byte >> 1] = f2bf(W1[kk * 128 + nn]);
    }
    for (int idx = t; idx < 64 * 128; idx += total) {
        int nn = idx >> 7, kk = idx & 127;
        uint byte = (uint)nn * 256u + (uint)kk * 2u;
        byte ^= (uint)((nn & 7) << 4);
        Wt2s[byte >> 1] = f2bf(W2[kk * 64 + nn]);
    }
}

// ---------------- MFMA GEMM: H[n x NCOLS] = bf16(X[n x 128]) @ W ----------------
// mfma_f32_16x16x32_bf16: A row=lane&15, k=(lane>>4)*8+i ; B col=lane&15, same k ;
// D col=lane&15, row=(lane>>4)*4+reg

template <int NCOLS, bool IN_BF16>
__launch_bounds__(256)
__global__ void gemm_mfma(const void* __restrict__ Xv, const ushort* __restrict__ Wimg,
                          ushort* __restrict__ H, int n) {
    constexpr int NT = NCOLS / 16;
    __shared__ ushort sW[NCOLS * 128];
    {
        const uint4* src = (const uint4*)Wimg;
        uint4* dst = (uint4*)sW;
        constexpr int NV = NCOLS * 128 * 2 / 16;
        for (int i = threadIdx.x; i < NV; i += 256) dst[i] = src[i];
    }
    __syncthreads();

    const int w  = threadIdx.x >> 6;
    const int l  = threadIdx.x & 63;
    const int lm = l & 15, lk = l >> 4;
    const int row_base = blockIdx.x * 128 + w * 32;

    f32x4 acc[2][NT];
#pragma unroll
    for (int mt = 0; mt < 2; ++mt)
#pragma unroll
        for (int nt = 0; nt < NT; ++nt) {
            f32x4 z = {0.f, 0.f, 0.f, 0.f};
            acc[mt][nt] = z;
        }

    int r0 = row_base + lm;
    int r1 = row_base + 16 + lm;
    int r0c = r0 < n ? r0 : n - 1;
    int r1c = r1 < n ? r1 : n - 1;

#pragma unroll
    for (int kb = 0; kb < 4; ++kb) {
        short8v a0, a1;
        if constexpr (IN_BF16) {
            const ushort* X = (const ushort*)Xv;
            a0 = *(const short8v*)(X + (size_t)r0c * 128 + kb * 32 + lk * 8);
            a1 = *(const short8v*)(X + (size_t)r1c * 128 + kb * 32 + lk * 8);
        } else {
            const float* X = (const float*)Xv;
            const float* p0 = X + (size_t)r0c * 128 + kb * 32 + lk * 8;
            const float* p1 = X + (size_t)r1c * 128 + kb * 32 + lk * 8;
            float4 u0 = *(const float4*)p0;
            float4 v0 = *(const float4*)(p0 + 4);
            float4 u1 = *(const float4*)p1;
            float4 v1 = *(const float4*)(p1 + 4);
            a0[0] = (short)f2bf(u0.x); a0[1] = (short)f2bf(u0.y);
            a0[2] = (short)f2bf(u0.z); a0[3] = (short)f2bf(u0.w);
            a0[4] = (short)f2bf(v0.x); a0[5] = (short)f2bf(v0.y);
            a0[6] = (short)f2bf(v0.z); a0[7] = (short)f2bf(v0.w);
            a1[0] = (short)f2bf(u1.x); a1[1] = (short)f2bf(u1.y);
            a1[2] = (short)f2bf(u1.z); a1[3] = (short)f2bf(u1.w);
            a1[4] = (short)f2bf(v1.x); a1[5] = (short)f2bf(v1.y);
            a1[6] = (short)f2bf(v1.z); a1[7] = (short)f2bf(v1.w);
        }
#pragma unroll
        for (int nt = 0; nt < NT; ++nt) {
            int nn = nt * 16 + lm;
            uint byte = (uint)nn * 256u + (uint)kb * 64u + (uint)lk * 16u;
            byte ^= (uint)((nn & 7) << 4);
            short8v b = *(const short8v*)((const char*)sW + byte);
            acc[0][nt] = __builtin_amdgcn_mfma_f32_16x16x32_bf16(a0, b, acc[0][nt], 0, 0, 0);
            acc[1][nt] = __builtin_amdgcn_mfma_f32_16x16x32_bf16(a1, b, acc[1][nt], 0, 0, 0);
        }
    }

#pragma unroll
    for (int mt = 0; mt < 2; ++mt)
#pragma unroll
        for (int nt = 0; nt < NT; ++nt)
#pragma unroll
            for (int r = 0; r < 4; ++r) {
                int row = row_base + mt * 16 + lk * 4 + r;
                if (row < n) H[(size_t)row * NCOLS + nt * 16 + lm] = f2bf(acc[mt][nt][r]);
            }
}

// ---------------- aggregation (bf16 gather, 8 gathers in flight incl. tails) ----------------
// Zero-init metadata makes out-of-range lanes gather H[0] with w=0 (L1-hit no-op),
// so every 16-edge batch runs the same fully-unrolled 8-iteration body.

template <bool RELU>
__launch_bounds__(256)
__global__ void agg128(const ushort* __restrict__ H, const int* __restrict__ rp,
                       const int2* __restrict__ edata, const float* __restrict__ bias,
                       ushort* __restrict__ out, int n) {
    int gw = (blockIdx.x * 256 + threadIdx.x) >> 6;
    int lane = threadIdx.x & 63;
    if (gw >= n) return;
    const int h = lane >> 5, c = lane & 31;
    int e = rp[gw], end = rp[gw + 1];
    float a0 = 0.f, a1 = 0.f, a2 = 0.f, a3 = 0.f;

    for (; e < end; e += 16) {
        int rem = end - e;                      // >= 1
        int2 md = make_int2(0, 0);
        if (lane < rem && lane < 16) md = edata[e + lane];
#pragma unroll
        for (int j = 0; j < 8; ++j) {
            int   si = __shfl(md.x, 2 * j + h);
            float w  = __int_as_float(__shfl(md.y, 2 * j + h));
            uint2 hv = *(const uint2*)&H[(size_t)si * 128 + c * 4];
            a0 += w * bf2f((ushort)hv.x); a1 += w * bf2f((ushort)(hv.x >> 16));
            a2 += w * bf2f((ushort)hv.y); a3 += w * bf2f((ushort)(hv.y >> 16));
        }
    }
    a0 += __shfl_xor(a0, 32); a1 += __shfl_xor(a1, 32);
    a2 += __shfl_xor(a2, 32); a3 += __shfl_xor(a3, 32);
    if (h == 0) {
        a0 += bias[c * 4 + 0]; a1 += bias[c * 4 + 1];
        a2 += bias[c * 4 + 2]; a3 += bias[c * 4 + 3];
        if (RELU) {
            a0 = fmaxf(a0, 0.f); a1 = fmaxf(a1, 0.f);
            a2 = fmaxf(a2, 0.f); a3 = fmaxf(a3, 0.f);
        }
        uint2 pk;
        pk.x = (uint)f2bf(a0) | ((uint)f2bf(a1) << 16);
        pk.y = (uint)f2bf(a2) | ((uint)f2bf(a3) << 16);
        *(uint2*)&out[(size_t)gw * 128 + c * 4] = pk;
    }
}

__launch_bounds__(256)
__global__ void agg64(const ushort* __restrict__ H, const int* __restrict__ rp,
                      const int2* __restrict__ edata, const float* __restrict__ bias,
                      float* __restrict__ out, int n) {
    int gw = (blockIdx.x * 256 + threadIdx.x) >> 6;
    int lane = threadIdx.x & 63;
    if (gw >= n) return;
    const int q = lane >> 4, c = lane & 15;
    int e = rp[gw], end = rp[gw + 1];
    float a0 = 0.f, a1 = 0.f, a2 = 0.f, a3 = 0.f;

    for (; e < end; e += 16) {
        int rem = end - e;
        int2 md = make_int2(0, 0);
        if (lane < rem && lane < 16) md = edata[e + lane];
#pragma unroll
        for (int j = 0; j < 4; ++j) {
            int   si = __shfl(md.x, 4 * j + q);
            float w  = __int_as_float(__shfl(md.y, 4 * j + q));
            uint2 hv = *(const uint2*)&H[(size_t)si * 64 + c * 4];
            a0 += w * bf2f((ushort)hv.x); a1 += w * bf2f((ushort)(hv.x >> 16));
            a2 += w * bf2f((ushort)hv.y); a3 += w * bf2f((ushort)(hv.y >> 16));
        }
    }
    a0 += __shfl_xor(a0, 16); a0 += __shfl_xor(a0, 32);
    a1 += __shfl_xor(a1, 16); a1 += __shfl_xor(a1, 32);
    a2 += __shfl_xor(a2, 16); a2 += __shfl_xor(a2, 32);
    a3 += __shfl_xor(a3, 16); a3 += __shfl_xor(a3, 32);
    if (q == 0) {
        a0 += bias[c * 4 + 0]; a1 += bias[c * 4 + 1];
        a2 += bias[c * 4 + 2]; a3 += bias[c * 4 + 3];
        *(float4*)&out[(size_t)gw * 64 + c * 4] = make_float4(a0, a1, a2, a3);
    }
}

__global__ void zero_out(float* __restrict__ out, int n) {
    int i = blockIdx.x * 256 + threadIdx.x;
    if (i < n) out[i] = 0.f;
}

// ---------------- launch ----------------

extern "C" void kernel_launch(void* const* d_in, const int* in_sizes, int n_in,
                              void* d_out, int out_size, void* d_ws, size_t ws_size,
                              hipStream_t stream) {
    const float* x  = (const float*)d_in[0];
    const int*   ei = (const int*)d_in[1];
    const float* W1 = (const float*)d_in[2];
    const float* b1 = (const float*)d_in[3];
    const float* W2 = (const float*)d_in[4];
    const float* b2 = (const float*)d_in[5];
    float* out = (float*)d_out;

    const int N = in_sizes[0] / 128;
    const int E = in_sizes[1] / 2;
    const int* srcp = ei;
    const int* dstp = ei + E;

    char* base = (char*)d_ws;
    size_t off = 0;
    auto alloc = [&](size_t bytes) -> void* {
        void* p = base + off;
        off += (bytes + 15) & ~(size_t)15;
        return p;
    };
    ushort* H1   = (ushort*)alloc((size_t)N * 128 * 2);
    ushort* A1   = (ushort*)alloc((size_t)N * 128 * 2);   // also aliases binning tmps (dead before agg128)
    ushort* Wt1s = (ushort*)alloc(128 * 128 * 2);
    ushort* Wt2s = (ushort*)alloc(64 * 128 * 2);
    float*  dinv = (float*)alloc((size_t)N * 4);
    int*    cnt  = (int*)alloc((size_t)N * 4);
    int*    rp   = (int*)alloc((size_t)(N + 1) * 4);
    int*    bsum = (int*)alloc(1024 * 4);
    int*    bcnt = (int*)alloc(MAXB * 4);
    int*    bcur = (int*)alloc(MAXB * 4);
    int2*   edata= (int2*)alloc((size_t)(E + N) * 8);
    ushort* H2   = H1;   // reuse layer-1 buffer

    // binning tmps alias A1 (need E*12 bytes <= N*256 bytes)
    int2* tsw  = (int2*)A1;
    int*  tdst = (int*)((char*)A1 + (size_t)E * 8);

    if (off > ws_size || (size_t)E * 12 > (size_t)N * 256) {
        zero_out<<<(out_size + 255) / 256, 256, 0, stream>>>(out, out_size);
        return;
    }

    int shift = 11;
    while (((N + (1 << shift) - 1) >> shift) > MAXB) ++shift;
    int nbk = (N + (1 << shift) - 1) >> shift;
    int nchunk = (E + 4095) / 4096;

    hipMemsetAsync(cnt, 0, (size_t)N * sizeof(int), stream);
    hipMemsetAsync(bcnt, 0, MAXB * sizeof(int), stream);
    hist_kernel<<<(E / 4 + 255) / 256, 256, 0, stream>>>(dstp, cnt, E);
    finalize_deg<<<(N + 255) / 256, 256, 0, stream>>>(cnt, dinv, N);
    int nb = (N + 1023) / 1024;
    scan_block<<<nb, 256, 0, stream>>>(cnt, rp, bsum, N);
    scan_bsum<<<1, 128, 0, stream>>>(bsum, nb);
    scan_add<<<(N + 255) / 256, 256, 0, stream>>>(rp, bsum, cnt, N);  // cnt becomes cursor

    bucket_hist<<<nchunk, 256, 0, stream>>>(dstp, bcnt, E, shift);
    bucket_scan<<<1, 64, 0, stream>>>(bcnt, bcur, nbk);
    bucket_scatter<<<nchunk, 256, 0, stream>>>(srcp, dstp, dinv, bcur, tsw, tdst, E, shift);
    fill_final<<<(E + 255) / 256, 256, 0, stream>>>(tsw, tdst, cnt, edata, E);
    fill_self<<<(N + 255) / 256, 256, 0, stream>>>(dinv, cnt, edata, N);
    prep_w<<<32, 256, 0, stream>>>(W1, W2, Wt1s, Wt2s);

    gemm_mfma<128, false><<<(N + 127) / 128, 256, 0, stream>>>(x, Wt1s, H1, N);
    agg128<true><<<(N + 3) / 4, 256, 0, stream>>>(H1, rp, edata, b1, A1, N);
    gemm_mfma<64, true><<<(N + 127) / 128, 256, 0, stream>>>(A1, Wt2s, H2, N);
    agg64<<<(N + 3) / 4, 256, 0, stream>>>(H2, rp, edata, b2, out, N);
}

// Round 5
// 282.566 us; speedup vs baseline: 1.7994x; 1.1601x over previous
//
#include <hip/hip_runtime.h>

typedef unsigned int uint;
typedef unsigned short ushort;
typedef __attribute__((ext_vector_type(8))) short short8v;
typedef __attribute__((ext_vector_type(4))) float f32x4;

#define NBMAX 512      // max coarse buckets (bucket = 256 nodes, N <= 131072)
#define BSHIFT 8       // 256 nodes per bucket

__device__ __forceinline__ ushort f2bf(float f) {
    uint u = __float_as_uint(f);
    u += 0x7fffu + ((u >> 16) & 1u);   // round-to-nearest-even
    return (ushort)(u >> 16);
}
__device__ __forceinline__ float bf2f(ushort h) {
    return __uint_as_float(((uint)h) << 16);
}

// ---------------- degree (for dinv) ----------------

__global__ void hist_kernel(const int* __restrict__ dst, int* __restrict__ cnt, int E) {
    int i = (blockIdx.x * 256 + threadIdx.x) * 4;
    if (i + 4 <= E) {
        int4 d = *(const int4*)&dst[i];
        atomicAdd(&cnt[d.x], 1);
        atomicAdd(&cnt[d.y], 1);
        atomicAdd(&cnt[d.z], 1);
        atomicAdd(&cnt[d.w], 1);
    } else {
        for (int k = i; k < E; ++k) atomicAdd(&cnt[dst[k]], 1);
    }
}

__global__ void finalize_deg(const int* __restrict__ cnt, float* __restrict__ dinv, int n) {
    int i = blockIdx.x * 256 + threadIdx.x;
    if (i >= n) return;
    dinv[i] = rsqrtf((float)(cnt[i] + 1));   // + self loop
}

// ---------------- binned CSR build ----------------
// Pass A: bin edges by coarse bucket (dst>>BSHIFT); record = {src | locdst<<17, w}.

__global__ void bucket_hist(const int* __restrict__ dst, int* __restrict__ bcnt,
                            int E, int nbk) {
    __shared__ int s[NBMAX];
    int t = threadIdx.x;
    for (int i = t; i < nbk; i += 256) s[i] = 0;
    __syncthreads();
    int i0 = blockIdx.x * 4096 + t;
#pragma unroll
    for (int k = 0; k < 16; ++k) {
        int i = i0 + k * 256;
        if (i < E) atomicAdd(&s[dst[i] >> BSHIFT], 1);
    }
    __syncthreads();
    for (int i = t; i < nbk; i += 256) if (s[i] > 0) atomicAdd(&bcnt[i], s[i]);
}

// single block, 512 threads: exclusive scan bcnt -> bstart (kept) and bcur (mutated later)
__global__ void bucket_scan(const int* __restrict__ bcnt, int* __restrict__ bstart,
                            int* __restrict__ bcur, int nbk) {
    __shared__ int s[512];
    int t = threadIdx.x;
    int v = (t < nbk) ? bcnt[t] : 0;
    s[t] = v;
    __syncthreads();
    for (int o = 1; o < 512; o <<= 1) {
        int tv = (t >= o) ? s[t - o] : 0;
        __syncthreads();
        s[t] += tv;
        __syncthreads();
    }
    if (t < nbk) {
        int ex = s[t] - v;
        bstart[t] = ex;
        bcur[t] = ex;
    }
}

__global__ void bucket_scatter(const int* __restrict__ src, const int* __restrict__ dst,
                               const float* __restrict__ dinv, int* __restrict__ bcur,
                               int2* __restrict__ tsw, int E) {
    __shared__ int cnt[NBMAX];
    __shared__ int base[NBMAX];
    int t = threadIdx.x;
    for (int i = t; i < NBMAX; i += 256) cnt[i] = 0;
    __syncthreads();
    int i0 = blockIdx.x * 4096 + t;
    int p_[16], b_[16], r_[16];
    float w_[16];
#pragma unroll
    for (int k = 0; k < 16; ++k) {
        int i = i0 + k * 256;
        if (i < E) {
            int s = src[i], d = dst[i];
            int bb = d >> BSHIFT;
            b_[k] = bb;
            p_[k] = s | ((d & ((1 << BSHIFT) - 1)) << 17);
            w_[k] = dinv[s] * dinv[d];
            r_[k] = atomicAdd(&cnt[bb], 1);
        } else {
            b_[k] = -1;
        }
    }
    __syncthreads();
    for (int i = t; i < NBMAX; i += 256) if (cnt[i] > 0) base[i] = atomicAdd(&bcur[i], cnt[i]);
    __syncthreads();
#pragma unroll
    for (int k = 0; k < 16; ++k) {
        if (b_[k] >= 0) {
            int p = base[b_[k]] + r_[k];
            tsw[p] = make_int2(p_[k], __float_as_int(w_[k]));
        }
    }
}

// Pass B: one block per bucket. LDS counting-sort by local dst; emits rp, self-loops,
// and the bucket's contiguous edata region (single-XCD window -> dense writeback).
__global__ void sort_bucket(const int2* __restrict__ tsw, const int* __restrict__ bstart,
                            const float* __restrict__ dinv, int* __restrict__ rp,
                            int2* __restrict__ edata, int N, int E, int nbk) {
    __shared__ int cnt[256];
    __shared__ int cursor[256];
    int b = blockIdx.x;
    int t = threadIdx.x;
    int estart = bstart[b];
    int eend = (b + 1 < nbk) ? bstart[b + 1] : E;

    cnt[t] = 0;
    __syncthreads();
    for (int i = estart + t; i < eend; i += 256) {
        uint p = (uint)tsw[i].x;
        atomicAdd(&cnt[p >> 17], 1);
    }
    __syncthreads();

    int node = (b << BSHIFT) + t;
    int self = (node < N) ? 1 : 0;
    int v = cnt[t] + self;
    cursor[t] = v;
    __syncthreads();
    for (int o = 1; o < 256; o <<= 1) {
        int tv = (t >= o) ? cursor[t - o] : 0;
        __syncthreads();
        cursor[t] += tv;
        __syncthreads();
    }
    int ex = cursor[t] - v;                       // exclusive local offset
    int gbase = estart + (b << BSHIFT);           // edges + self loops before this bucket

    if (node < N) {
        rp[node] = gbase + ex;
        float w = dinv[node];
        edata[gbase + ex] = make_int2(node, __float_as_int(w * w));  // self loop at slot 0
    }
    if (b == nbk - 1 && t == 0) rp[N] = E + N;
    cursor[t] = ex + self;
    __syncthreads();

    for (int i = estart + t; i < eend; i += 256) {
        int2 rec = tsw[i];
        uint p = (uint)rec.x;
        int pos = gbase + atomicAdd(&cursor[p >> 17], 1);
        edata[pos] = make_int2((int)(p & 0x1FFFFu), rec.y);
    }
}

// ---------------- W pre-transpose/convert/swizzle: [n][k] bf16 image, byte ^ ((n&7)<<4) ----------------

__global__ void prep_w(const float* __restrict__ W1, const float* __restrict__ W2,
                       ushort* __restrict__ Wt1s, ushort* __restrict__ Wt2s) {
    int t = blockIdx.x * 256 + threadIdx.x;
    int total = gridDim.x * 256;
    for (int idx = t; idx < 128 * 128; idx += total) {
        int nn = idx >> 7, kk = idx & 127;
        uint byte = (uint)nn * 256u + (uint)kk * 2u;
        byte ^= (uint)((nn & 7) << 4);
        Wt1s[byte >> 1] = f2bf(W1[kk * 128 + nn]);
    }
    for (int idx = t; idx < 64 * 128; idx += total) {
        int nn = idx >> 7, kk = idx & 127;
        uint byte = (uint)nn * 256u + (uint)kk * 2u;
        byte ^= (uint)((nn & 7) << 4);
        Wt2s[byte >> 1] = f2bf(W2[kk * 64 + nn]);
    }
}

// ---------------- MFMA GEMM: H[n x NCOLS] = bf16(X[n x 128]) @ W ----------------
// mfma_f32_16x16x32_bf16: A row=lane&15, k=(lane>>4)*8+i ; B col=lane&15, same k ;
// D col=lane&15, row=(lane>>4)*4+reg

template <int NCOLS, bool IN_BF16>
__launch_bounds__(256)
__global__ void gemm_mfma(const void* __restrict__ Xv, const ushort* __restrict__ Wimg,
                          ushort* __restrict__ H, int n) {
    constexpr int NT = NCOLS / 16;
    __shared__ ushort sW[NCOLS * 128];
    {
        const uint4* src = (const uint4*)Wimg;
        uint4* dst = (uint4*)sW;
        constexpr int NV = NCOLS * 128 * 2 / 16;
        for (int i = threadIdx.x; i < NV; i += 256) dst[i] = src[i];
    }
    __syncthreads();

    const int w  = threadIdx.x >> 6;
    const int l  = threadIdx.x & 63;
    const int lm = l & 15, lk = l >> 4;
    const int row_base = blockIdx.x * 128 + w * 32;

    f32x4 acc[2][NT];
#pragma unroll
    for (int mt = 0; mt < 2; ++mt)
#pragma unroll
        for (int nt = 0; nt < NT; ++nt) {
            f32x4 z = {0.f, 0.f, 0.f, 0.f};
            acc[mt][nt] = z;
        }

    int r0 = row_base + lm;
    int r1 = row_base + 16 + lm;
    int r0c = r0 < n ? r0 : n - 1;
    int r1c = r1 < n ? r1 : n - 1;

#pragma unroll
    for (int kb = 0; kb < 4; ++kb) {
        short8v a0, a1;
        if constexpr (IN_BF16) {
            const ushort* X = (const ushort*)Xv;
            a0 = *(const short8v*)(X + (size_t)r0c * 128 + kb * 32 + lk * 8);
            a1 = *(const short8v*)(X + (size_t)r1c * 128 + kb * 32 + lk * 8);
        } else {
            const float* X = (const float*)Xv;
            const float* p0 = X + (size_t)r0c * 128 + kb * 32 + lk * 8;
            const float* p1 = X + (size_t)r1c * 128 + kb * 32 + lk * 8;
            float4 u0 = *(const float4*)p0;
            float4 v0 = *(const float4*)(p0 + 4);
            float4 u1 = *(const float4*)p1;
            float4 v1 = *(const float4*)(p1 + 4);
            a0[0] = (short)f2bf(u0.x); a0[1] = (short)f2bf(u0.y);
            a0[2] = (short)f2bf(u0.z); a0[3] = (short)f2bf(u0.w);
            a0[4] = (short)f2bf(v0.x); a0[5] = (short)f2bf(v0.y);
            a0[6] = (short)f2bf(v0.z); a0[7] = (short)f2bf(v0.w);
            a1[0] = (short)f2bf(u1.x); a1[1] = (short)f2bf(u1.y);
            a1[2] = (short)f2bf(u1.z); a1[3] = (short)f2bf(u1.w);
            a1[4] = (short)f2bf(v1.x); a1[5] = (short)f2bf(v1.y);
            a1[6] = (short)f2bf(v1.z); a1[7] = (short)f2bf(v1.w);
        }
#pragma unroll
        for (int nt = 0; nt < NT; ++nt) {
            int nn = nt * 16 + lm;
            uint byte = (uint)nn * 256u + (uint)kb * 64u + (uint)lk * 16u;
            byte ^= (uint)((nn & 7) << 4);
            short8v b = *(const short8v*)((const char*)sW + byte);
            acc[0][nt] = __builtin_amdgcn_mfma_f32_16x16x32_bf16(a0, b, acc[0][nt], 0, 0, 0);
            acc[1][nt] = __builtin_amdgcn_mfma_f32_16x16x32_bf16(a1, b, acc[1][nt], 0, 0, 0);
        }
    }

#pragma unroll
    for (int mt = 0; mt < 2; ++mt)
#pragma unroll
        for (int nt = 0; nt < NT; ++nt)
#pragma unroll
            for (int r = 0; r < 4; ++r) {
                int row = row_base + mt * 16 + lk * 4 + r;
                if (row < n) H[(size_t)row * NCOLS + nt * 16 + lm] = f2bf(acc[mt][nt][r]);
            }
}

// ---------------- aggregation (bf16 gather, 8 gathers in flight incl. tails) ----------------

template <bool RELU>
__launch_bounds__(256)
__global__ void agg128(const ushort* __restrict__ H, const int* __restrict__ rp,
                       const int2* __restrict__ edata, const float* __restrict__ bias,
                       ushort* __restrict__ out, int n) {
    int gw = (blockIdx.x * 256 + threadIdx.x) >> 6;
    int lane = threadIdx.x & 63;
    if (gw >= n) return;
    const int h = lane >> 5, c = lane & 31;
    int e = rp[gw], end = rp[gw + 1];
    float a0 = 0.f, a1 = 0.f, a2 = 0.f, a3 = 0.f;

    for (; e < end; e += 16) {
        int rem = end - e;                      // >= 1
        int2 md = make_int2(0, 0);
        if (lane < rem && lane < 16) md = edata[e + lane];
#pragma unroll
        for (int j = 0; j < 8; ++j) {
            int   si = __shfl(md.x, 2 * j + h);
            float w  = __int_as_float(__shfl(md.y, 2 * j + h));
            uint2 hv = *(const uint2*)&H[(size_t)si * 128 + c * 4];
            a0 += w * bf2f((ushort)hv.x); a1 += w * bf2f((ushort)(hv.x >> 16));
            a2 += w * bf2f((ushort)hv.y); a3 += w * bf2f((ushort)(hv.y >> 16));
        }
    }
    a0 += __shfl_xor(a0, 32); a1 += __shfl_xor(a1, 32);
    a2 += __shfl_xor(a2, 32); a3 += __shfl_xor(a3, 32);
    if (h == 0) {
        a0 += bias[c * 4 + 0]; a1 += bias[c * 4 + 1];
        a2 += bias[c * 4 + 2]; a3 += bias[c * 4 + 3];
        if (RELU) {
            a0 = fmaxf(a0, 0.f); a1 = fmaxf(a1, 0.f);
            a2 = fmaxf(a2, 0.f); a3 = fmaxf(a3, 0.f);
        }
        uint2 pk;
        pk.x = (uint)f2bf(a0) | ((uint)f2bf(a1) << 16);
        pk.y = (uint)f2bf(a2) | ((uint)f2bf(a3) << 16);
        *(uint2*)&out[(size_t)gw * 128 + c * 4] = pk;
    }
}

__launch_bounds__(256)
__global__ void agg64(const ushort* __restrict__ H, const int* __restrict__ rp,
                      const int2* __restrict__ edata, const float* __restrict__ bias,
                      float* __restrict__ out, int n) {
    int gw = (blockIdx.x * 256 + threadIdx.x) >> 6;
    int lane = threadIdx.x & 63;
    if (gw >= n) return;
    const int q = lane >> 4, c = lane & 15;
    int e = rp[gw], end = rp[gw + 1];
    float a0 = 0.f, a1 = 0.f, a2 = 0.f, a3 = 0.f;

    for (; e < end; e += 16) {
        int rem = end - e;
        int2 md = make_int2(0, 0);
        if (lane < rem && lane < 16) md = edata[e + lane];
#pragma unroll
        for (int j = 0; j < 4; ++j) {
            int   si = __shfl(md.x, 4 * j + q);
            float w  = __int_as_float(__shfl(md.y, 4 * j + q));
            uint2 hv = *(const uint2*)&H[(size_t)si * 64 + c * 4];
            a0 += w * bf2f((ushort)hv.x); a1 += w * bf2f((ushort)(hv.x >> 16));
            a2 += w * bf2f((ushort)hv.y); a3 += w * bf2f((ushort)(hv.y >> 16));
        }
    }
    a0 += __shfl_xor(a0, 16); a0 += __shfl_xor(a0, 32);
    a1 += __shfl_xor(a1, 16); a1 += __shfl_xor(a1, 32);
    a2 += __shfl_xor(a2, 16); a2 += __shfl_xor(a2, 32);
    a3 += __shfl_xor(a3, 16); a3 += __shfl_xor(a3, 32);
    if (q == 0) {
        a0 += bias[c * 4 + 0]; a1 += bias[c * 4 + 1];
        a2 += bias[c * 4 + 2]; a3 += bias[c * 4 + 3];
        *(float4*)&out[(size_t)gw * 64 + c * 4] = make_float4(a0, a1, a2, a3);
    }
}

__global__ void zero_out(float* __restrict__ out, int n) {
    int i = blockIdx.x * 256 + threadIdx.x;
    if (i < n) out[i] = 0.f;
}

// ---------------- launch ----------------

extern "C" void kernel_launch(void* const* d_in, const int* in_sizes, int n_in,
                              void* d_out, int out_size, void* d_ws, size_t ws_size,
                              hipStream_t stream) {
    const float* x  = (const float*)d_in[0];
    const int*   ei = (const int*)d_in[1];
    const float* W1 = (const float*)d_in[2];
    const float* b1 = (const float*)d_in[3];
    const float* W2 = (const float*)d_in[4];
    const float* b2 = (const float*)d_in[5];
    float* out = (float*)d_out;

    const int N = in_sizes[0] / 128;
    const int E = in_sizes[1] / 2;
    const int* srcp = ei;
    const int* dstp = ei + E;

    char* base = (char*)d_ws;
    size_t off = 0;
    auto alloc = [&](size_t bytes) -> void* {
        void* p = base + off;
        off += (bytes + 15) & ~(size_t)15;
        return p;
    };
    ushort* H1    = (ushort*)alloc((size_t)N * 128 * 2);
    ushort* A1    = (ushort*)alloc((size_t)N * 128 * 2);   // aliases tsw (dead before agg128)
    ushort* Wt1s  = (ushort*)alloc(128 * 128 * 2);
    ushort* Wt2s  = (ushort*)alloc(64 * 128 * 2);
    float*  dinv  = (float*)alloc((size_t)N * 4);
    int*    cnt   = (int*)alloc((size_t)N * 4);
    int*    rp    = (int*)alloc((size_t)(N + 1) * 4);
    int*    bcnt  = (int*)alloc(NBMAX * 4);
    int*    bstart= (int*)alloc(NBMAX * 4);
    int*    bcur  = (int*)alloc(NBMAX * 4);
    int2*   edata = (int2*)alloc((size_t)(E + N) * 8);
    ushort* H2    = H1;   // reuse layer-1 buffer

    int2* tsw = (int2*)A1;   // E records of 8B; needs E*8 <= N*256

    int nbk = (N + (1 << BSHIFT) - 1) >> BSHIFT;
    if (off > ws_size || (size_t)E * 8 > (size_t)N * 256 || N > (1 << 17) || nbk > NBMAX) {
        zero_out<<<(out_size + 255) / 256, 256, 0, stream>>>(out, out_size);
        return;
    }
    int nchunk = (E + 4095) / 4096;

    hipMemsetAsync(cnt, 0, (size_t)N * sizeof(int), stream);
    hipMemsetAsync(bcnt, 0, NBMAX * sizeof(int), stream);
    hist_kernel<<<(E / 4 + 255) / 256, 256, 0, stream>>>(dstp, cnt, E);
    finalize_deg<<<(N + 255) / 256, 256, 0, stream>>>(cnt, dinv, N);

    bucket_hist<<<nchunk, 256, 0, stream>>>(dstp, bcnt, E, nbk);
    bucket_scan<<<1, 512, 0, stream>>>(bcnt, bstart, bcur, nbk);
    bucket_scatter<<<nchunk, 256, 0, stream>>>(srcp, dstp, dinv, bcur, tsw, E);
    sort_bucket<<<nbk, 256, 0, stream>>>(tsw, bstart, dinv, rp, edata, N, E, nbk);
    prep_w<<<32, 256, 0, stream>>>(W1, W2, Wt1s, Wt2s);

    gemm_mfma<128, false><<<(N + 127) / 128, 256, 0, stream>>>(x, Wt1s, H1, N);
    agg128<true><<<(N + 3) / 4, 256, 0, stream>>>(H1, rp, edata, b1, A1, N);
    gemm_mfma<64, true><<<(N + 127) / 128, 256, 0, stream>>>(A1, Wt2s, H2, N);
    agg64<<<(N + 3) / 4, 256, 0, stream>>>(H2, rp, edata, b2, out, N);
}

// Round 6
// 212.069 us; speedup vs baseline: 2.3976x; 1.3324x over previous
//
#include <hip/hip_runtime.h>

typedef unsigned int uint;
typedef unsigned short ushort;
typedef __attribute__((ext_vector_type(8))) short short8v;
typedef __attribute__((ext_vector_type(4))) float f32x4;

#define NBMAX 512      // max coarse buckets (bucket = 256 nodes, N <= 131072)
#define BSHIFT 8       // 256 nodes per bucket

__device__ __forceinline__ ushort f2bf(float f) {
    uint u = __float_as_uint(f);
    u += 0x7fffu + ((u >> 16) & 1u);   // round-to-nearest-even
    return (ushort)(u >> 16);
}
__device__ __forceinline__ float bf2f(ushort h) {
    return __uint_as_float(((uint)h) << 16);
}

// ---------------- binned CSR build ----------------
// Pass A: bin edges by coarse bucket (dst>>BSHIFT); record = src | locdst<<17 (4B).

__global__ void bucket_hist(const int* __restrict__ dst, int* __restrict__ bcnt,
                            int E, int nbk) {
    __shared__ int s[NBMAX];
    int t = threadIdx.x;
    for (int i = t; i < nbk; i += 256) s[i] = 0;
    __syncthreads();
    int i0 = blockIdx.x * 4096 + t;
#pragma unroll
    for (int k = 0; k < 16; ++k) {
        int i = i0 + k * 256;
        if (i < E) atomicAdd(&s[dst[i] >> BSHIFT], 1);
    }
    __syncthreads();
    for (int i = t; i < nbk; i += 256) if (s[i] > 0) atomicAdd(&bcnt[i], s[i]);
}

// single block, 512 threads: exclusive scan bcnt -> bstart (kept) and bcur (mutated later)
__global__ void bucket_scan(const int* __restrict__ bcnt, int* __restrict__ bstart,
                            int* __restrict__ bcur, int nbk) {
    __shared__ int s[512];
    int t = threadIdx.x;
    int v = (t < nbk) ? bcnt[t] : 0;
    s[t] = v;
    __syncthreads();
    for (int o = 1; o < 512; o <<= 1) {
        int tv = (t >= o) ? s[t - o] : 0;
        __syncthreads();
        s[t] += tv;
        __syncthreads();
    }
    if (t < nbk) {
        int ex = s[t] - v;
        bstart[t] = ex;
        bcur[t] = ex;
    }
}

__global__ void bucket_scatter(const int* __restrict__ src, const int* __restrict__ dst,
                               int* __restrict__ bcur, int* __restrict__ tsw, int E) {
    __shared__ int cnt[NBMAX];
    __shared__ int base[NBMAX];
    int t = threadIdx.x;
    for (int i = t; i < NBMAX; i += 256) cnt[i] = 0;
    __syncthreads();
    int i0 = blockIdx.x * 4096 + t;
    int p_[16], b_[16], r_[16];
#pragma unroll
    for (int k = 0; k < 16; ++k) {
        int i = i0 + k * 256;
        if (i < E) {
            int s = src[i], d = dst[i];
            int bb = d >> BSHIFT;
            b_[k] = bb;
            p_[k] = s | ((d & ((1 << BSHIFT) - 1)) << 17);
            r_[k] = atomicAdd(&cnt[bb], 1);
        } else {
            b_[k] = -1;
        }
    }
    __syncthreads();
    for (int i = t; i < NBMAX; i += 256) if (cnt[i] > 0) base[i] = atomicAdd(&bcur[i], cnt[i]);
    __syncthreads();
#pragma unroll
    for (int k = 0; k < 16; ++k) {
        if (b_[k] >= 0) {
            int p = base[b_[k]] + r_[k];
            tsw[p] = p_[k];
        }
    }
}

// Pass B: one block per bucket. LDS counting-sort by local dst. The LDS histogram IS
// the in-degree (all edges of a dst land in its bucket) -> emits dinv, rp, self-loops,
// and the bucket's contiguous edata region (single-XCD window -> dense writeback).
__global__ void sort_bucket(const int* __restrict__ tsw, const int* __restrict__ bstart,
                            float* __restrict__ dinv, int* __restrict__ rp,
                            int* __restrict__ edata, int N, int E, int nbk) {
    __shared__ int cnt[256];
    __shared__ int cursor[256];
    int b = blockIdx.x;
    int t = threadIdx.x;
    int estart = bstart[b];
    int eend = (b + 1 < nbk) ? bstart[b + 1] : E;

    cnt[t] = 0;
    __syncthreads();
    for (int i = estart + t; i < eend; i += 256) {
        atomicAdd(&cnt[(uint)tsw[i] >> 17], 1);
    }
    __syncthreads();

    int node = (b << BSHIFT) + t;
    int self = (node < N) ? 1 : 0;
    int deg = cnt[t];
    int v = deg + self;
    cursor[t] = v;
    __syncthreads();
    for (int o = 1; o < 256; o <<= 1) {
        int tv = (t >= o) ? cursor[t - o] : 0;
        __syncthreads();
        cursor[t] += tv;
        __syncthreads();
    }
    int ex = cursor[t] - v;                       // exclusive local offset
    int gbase = estart + (b << BSHIFT);           // edges + self loops before this bucket

    if (node < N) {
        dinv[node] = rsqrtf((float)(deg + 1));    // + self loop
        rp[node] = gbase + ex;
        edata[gbase + ex] = node;                 // self loop at slot 0 (src == dst)
    }
    if (b == nbk - 1 && t == 0) rp[N] = E + N;
    cursor[t] = ex + self;
    __syncthreads();

    for (int i = estart + t; i < eend; i += 256) {
        uint rec = (uint)tsw[i];
        int pos = gbase + atomicAdd(&cursor[rec >> 17], 1);
        edata[pos] = (int)(rec & 0x1FFFFu);
    }
}

// ---------------- W pre-transpose/convert/swizzle: [n][k] bf16 image, byte ^ ((n&7)<<4) ----------------

__global__ void prep_w(const float* __restrict__ W1, const float* __restrict__ W2,
                       ushort* __restrict__ Wt1s, ushort* __restrict__ Wt2s) {
    int t = blockIdx.x * 256 + threadIdx.x;
    int total = gridDim.x * 256;
    for (int idx = t; idx < 128 * 128; idx += total) {
        int nn = idx >> 7, kk = idx & 127;
        uint byte = (uint)nn * 256u + (uint)kk * 2u;
        byte ^= (uint)((nn & 7) << 4);
        Wt1s[byte >> 1] = f2bf(W1[kk * 128 + nn]);
    }
    for (int idx = t; idx < 64 * 128; idx += total) {
        int nn = idx >> 7, kk = idx & 127;
        uint byte = (uint)nn * 256u + (uint)kk * 2u;
        byte ^= (uint)((nn & 7) << 4);
        Wt2s[byte >> 1] = f2bf(W2[kk * 64 + nn]);
    }
}

// ---------------- MFMA GEMM: H[n x NCOLS] = bf16(X[n x 128]) @ W ----------------
// mfma_f32_16x16x32_bf16: A row=lane&15, k=(lane>>4)*8+i ; B col=lane&15, same k ;
// D col=lane&15, row=(lane>>4)*4+reg

template <int NCOLS, bool IN_BF16>
__launch_bounds__(256)
__global__ void gemm_mfma(const void* __restrict__ Xv, const ushort* __restrict__ Wimg,
                          ushort* __restrict__ H, int n) {
    constexpr int NT = NCOLS / 16;
    __shared__ ushort sW[NCOLS * 128];
    {
        const uint4* src = (const uint4*)Wimg;
        uint4* dst = (uint4*)sW;
        constexpr int NV = NCOLS * 128 * 2 / 16;
        for (int i = threadIdx.x; i < NV; i += 256) dst[i] = src[i];
    }
    __syncthreads();

    const int w  = threadIdx.x >> 6;
    const int l  = threadIdx.x & 63;
    const int lm = l & 15, lk = l >> 4;
    const int row_base = blockIdx.x * 128 + w * 32;

    f32x4 acc[2][NT];
#pragma unroll
    for (int mt = 0; mt < 2; ++mt)
#pragma unroll
        for (int nt = 0; nt < NT; ++nt) {
            f32x4 z = {0.f, 0.f, 0.f, 0.f};
            acc[mt][nt] = z;
        }

    int r0 = row_base + lm;
    int r1 = row_base + 16 + lm;
    int r0c = r0 < n ? r0 : n - 1;
    int r1c = r1 < n ? r1 : n - 1;

#pragma unroll
    for (int kb = 0; kb < 4; ++kb) {
        short8v a0, a1;
        if constexpr (IN_BF16) {
            const ushort* X = (const ushort*)Xv;
            a0 = *(const short8v*)(X + (size_t)r0c * 128 + kb * 32 + lk * 8);
            a1 = *(const short8v*)(X + (size_t)r1c * 128 + kb * 32 + lk * 8);
        } else {
            const float* X = (const float*)Xv;
            const float* p0 = X + (size_t)r0c * 128 + kb * 32 + lk * 8;
            const float* p1 = X + (size_t)r1c * 128 + kb * 32 + lk * 8;
            float4 u0 = *(const float4*)p0;
            float4 v0 = *(const float4*)(p0 + 4);
            float4 u1 = *(const float4*)p1;
            float4 v1 = *(const float4*)(p1 + 4);
            a0[0] = (short)f2bf(u0.x); a0[1] = (short)f2bf(u0.y);
            a0[2] = (short)f2bf(u0.z); a0[3] = (short)f2bf(u0.w);
            a0[4] = (short)f2bf(v0.x); a0[5] = (short)f2bf(v0.y);
            a0[6] = (short)f2bf(v0.z); a0[7] = (short)f2bf(v0.w);
            a1[0] = (short)f2bf(u1.x); a1[1] = (short)f2bf(u1.y);
            a1[2] = (short)f2bf(u1.z); a1[3] = (short)f2bf(u1.w);
            a1[4] = (short)f2bf(v1.x); a1[5] = (short)f2bf(v1.y);
            a1[6] = (short)f2bf(v1.z); a1[7] = (short)f2bf(v1.w);
        }
#pragma unroll
        for (int nt = 0; nt < NT; ++nt) {
            int nn = nt * 16 + lm;
            uint byte = (uint)nn * 256u + (uint)kb * 64u + (uint)lk * 16u;
            byte ^= (uint)((nn & 7) << 4);
            short8v b = *(const short8v*)((const char*)sW + byte);
            acc[0][nt] = __builtin_amdgcn_mfma_f32_16x16x32_bf16(a0, b, acc[0][nt], 0, 0, 0);
            acc[1][nt] = __builtin_amdgcn_mfma_f32_16x16x32_bf16(a1, b, acc[1][nt], 0, 0, 0);
        }
    }

#pragma unroll
    for (int mt = 0; mt < 2; ++mt)
#pragma unroll
        for (int nt = 0; nt < NT; ++nt)
#pragma unroll
            for (int r = 0; r < 4; ++r) {
                int row = row_base + mt * 16 + lk * 4 + r;
                if (row < n) H[(size_t)row * NCOLS + nt * 16 + lm] = f2bf(acc[mt][nt][r]);
            }
}

// ---------------- aggregation (bf16 gather; w = dinv[src]*dinv[dst] on the fly) ----------------

template <bool RELU>
__launch_bounds__(256)
__global__ void agg128(const ushort* __restrict__ H, const int* __restrict__ rp,
                       const int* __restrict__ edata, const float* __restrict__ dinv,
                       const float* __restrict__ bias, ushort* __restrict__ out, int n) {
    int gw = (blockIdx.x * 256 + threadIdx.x) >> 6;
    int lane = threadIdx.x & 63;
    if (gw >= n) return;
    const int h = lane >> 5, c = lane & 31;
    int e = rp[gw], end = rp[gw + 1];
    const float dg = dinv[gw];
    float a0 = 0.f, a1 = 0.f, a2 = 0.f, a3 = 0.f;

    for (; e < end; e += 16) {
        int rem = end - e;                      // >= 1
        int s = 0;
        float wl = 0.f;
        if (lane < rem && lane < 16) {
            s = edata[e + lane];
            wl = dinv[s];
        }
#pragma unroll
        for (int j = 0; j < 8; ++j) {
            int   si = __shfl(s, 2 * j + h);
            float w  = __shfl(wl, 2 * j + h) * dg;
            uint2 hv = *(const uint2*)&H[(size_t)si * 128 + c * 4];
            a0 += w * bf2f((ushort)hv.x); a1 += w * bf2f((ushort)(hv.x >> 16));
            a2 += w * bf2f((ushort)hv.y); a3 += w * bf2f((ushort)(hv.y >> 16));
        }
    }
    a0 += __shfl_xor(a0, 32); a1 += __shfl_xor(a1, 32);
    a2 += __shfl_xor(a2, 32); a3 += __shfl_xor(a3, 32);
    if (h == 0) {
        a0 += bias[c * 4 + 0]; a1 += bias[c * 4 + 1];
        a2 += bias[c * 4 + 2]; a3 += bias[c * 4 + 3];
        if (RELU) {
            a0 = fmaxf(a0, 0.f); a1 = fmaxf(a1, 0.f);
            a2 = fmaxf(a2, 0.f); a3 = fmaxf(a3, 0.f);
        }
        uint2 pk;
        pk.x = (uint)f2bf(a0) | ((uint)f2bf(a1) << 16);
        pk.y = (uint)f2bf(a2) | ((uint)f2bf(a3) << 16);
        *(uint2*)&out[(size_t)gw * 128 + c * 4] = pk;
    }
}

__launch_bounds__(256)
__global__ void agg64(const ushort* __restrict__ H, const int* __restrict__ rp,
                      const int* __restrict__ edata, const float* __restrict__ dinv,
                      const float* __restrict__ bias, float* __restrict__ out, int n) {
    int gw = (blockIdx.x * 256 + threadIdx.x) >> 6;
    int lane = threadIdx.x & 63;
    if (gw >= n) return;
    const int q = lane >> 4, c = lane & 15;
    int e = rp[gw], end = rp[gw + 1];
    const float dg = dinv[gw];
    float a0 = 0.f, a1 = 0.f, a2 = 0.f, a3 = 0.f;

    for (; e < end; e += 16) {
        int rem = end - e;
        int s = 0;
        float wl = 0.f;
        if (lane < rem && lane < 16) {
            s = edata[e + lane];
            wl = dinv[s];
        }
#pragma unroll
        for (int j = 0; j < 4; ++j) {
            int   si = __shfl(s, 4 * j + q);
            float w  = __shfl(wl, 4 * j + q) * dg;
            uint2 hv = *(const uint2*)&H[(size_t)si * 64 + c * 4];
            a0 += w * bf2f((ushort)hv.x); a1 += w * bf2f((ushort)(hv.x >> 16));
            a2 += w * bf2f((ushort)hv.y); a3 += w * bf2f((ushort)(hv.y >> 16));
        }
    }
    a0 += __shfl_xor(a0, 16); a0 += __shfl_xor(a0, 32);
    a1 += __shfl_xor(a1, 16); a1 += __shfl_xor(a1, 32);
    a2 += __shfl_xor(a2, 16); a2 += __shfl_xor(a2, 32);
    a3 += __shfl_xor(a3, 16); a3 += __shfl_xor(a3, 32);
    if (q == 0) {
        a0 += bias[c * 4 + 0]; a1 += bias[c * 4 + 1];
        a2 += bias[c * 4 + 2]; a3 += bias[c * 4 + 3];
        *(float4*)&out[(size_t)gw * 64 + c * 4] = make_float4(a0, a1, a2, a3);
    }
}

__global__ void zero_out(float* __restrict__ out, int n) {
    int i = blockIdx.x * 256 + threadIdx.x;
    if (i < n) out[i] = 0.f;
}

// ---------------- launch ----------------

extern "C" void kernel_launch(void* const* d_in, const int* in_sizes, int n_in,
                              void* d_out, int out_size, void* d_ws, size_t ws_size,
                              hipStream_t stream) {
    const float* x  = (const float*)d_in[0];
    const int*   ei = (const int*)d_in[1];
    const float* W1 = (const float*)d_in[2];
    const float* b1 = (const float*)d_in[3];
    const float* W2 = (const float*)d_in[4];
    const float* b2 = (const float*)d_in[5];
    float* out = (float*)d_out;

    const int N = in_sizes[0] / 128;
    const int E = in_sizes[1] / 2;
    const int* srcp = ei;
    const int* dstp = ei + E;

    char* base = (char*)d_ws;
    size_t off = 0;
    auto alloc = [&](size_t bytes) -> void* {
        void* p = base + off;
        off += (bytes + 15) & ~(size_t)15;
        return p;
    };
    ushort* H1    = (ushort*)alloc((size_t)N * 128 * 2);
    ushort* A1    = (ushort*)alloc((size_t)N * 128 * 2);   // aliases tsw (dead before agg128)
    ushort* Wt1s  = (ushort*)alloc(128 * 128 * 2);
    ushort* Wt2s  = (ushort*)alloc(64 * 128 * 2);
    float*  dinv  = (float*)alloc((size_t)N * 4);
    int*    rp    = (int*)alloc((size_t)(N + 1) * 4);
    int*    bcnt  = (int*)alloc(NBMAX * 4);
    int*    bstart= (int*)alloc(NBMAX * 4);
    int*    bcur  = (int*)alloc(NBMAX * 4);
    int*    edata = (int*)alloc((size_t)(E + N) * 4);
    ushort* H2    = H1;   // reuse layer-1 buffer

    int* tsw = (int*)A1;   // E records of 4B; needs E*4 <= N*256

    int nbk = (N + (1 << BSHIFT) - 1) >> BSHIFT;
    if (off > ws_size || (size_t)E * 4 > (size_t)N * 256 || N > (1 << 17) || nbk > NBMAX) {
        zero_out<<<(out_size + 255) / 256, 256, 0, stream>>>(out, out_size);
        return;
    }
    int nchunk = (E + 4095) / 4096;

    hipMemsetAsync(bcnt, 0, NBMAX * sizeof(int), stream);
    bucket_hist<<<nchunk, 256, 0, stream>>>(dstp, bcnt, E, nbk);
    bucket_scan<<<1, 512, 0, stream>>>(bcnt, bstart, bcur, nbk);
    bucket_scatter<<<nchunk, 256, 0, stream>>>(srcp, dstp, bcur, tsw, E);
    sort_bucket<<<nbk, 256, 0, stream>>>(tsw, bstart, dinv, rp, edata, N, E, nbk);
    prep_w<<<32, 256, 0, stream>>>(W1, W2, Wt1s, Wt2s);

    gemm_mfma<128, false><<<(N + 127) / 128, 256, 0, stream>>>(x, Wt1s, H1, N);
    agg128<true><<<(N + 3) / 4, 256, 0, stream>>>(H1, rp, edata, dinv, b1, A1, N);
    gemm_mfma<64, true><<<(N + 127) / 128, 256, 0, stream>>>(A1, Wt2s, H2, N);
    agg64<<<(N + 3) / 4, 256, 0, stream>>>(H2, rp, edata, dinv, b2, out, N);
}